// Round 2
// baseline (2346.780 us; speedup 1.0000x reference)
//
#include <hip/hip_runtime.h>

// Problem constants (fixed by the reference)
constexpr int N = 50000;
constexpr int E = 800000;
constexpr int G = 512;
constexpr int H = 128;
constexpr long long NH = (long long)N * H;   // 6,400,000 floats
constexpr float EPS = 1e-5f;

// ---------------------------------------------------------------------------
// vn[g][c] = vn_emb[c]
__global__ void k_init_vn(const float* __restrict__ vn_emb, float* __restrict__ vn) {
  int idx = blockIdx.x * 256 + threadIdx.x;   // G*H = 65536 exactly
  vn[idx] = vn_emb[idx & 127];
}

// h[r][:] += vn[batch[r]][:]  (float4-vectorized, grid covers N*32 float4s exactly)
__global__ void k_addvn(float* __restrict__ h, const float* __restrict__ vn,
                        const int* __restrict__ batch) {
  int i4 = blockIdx.x * 256 + threadIdx.x;
  int r = i4 >> 5;
  int b = batch[r];
  float4 hv = reinterpret_cast<float4*>(h)[i4];
  float4 vv = reinterpret_cast<const float4*>(vn)[(b << 5) + (i4 & 31)];
  hv.x += vv.x; hv.y += vv.y; hv.z += vv.z; hv.w += vv.w;
  reinterpret_cast<float4*>(h)[i4] = hv;
}

// ---------------------------------------------------------------------------
// Edge kernel: for each edge e: ev = edge_attr[e] @ We + be;
// msg = relu(h[src[e]] + ev); agg[dst[e]] += msg (atomic).
// We (16x128) staged in LDS. Each half-block (128 threads) owns one edge.
__global__ void k_edge(const float* __restrict__ edge_attr,
                       const float* __restrict__ We, const float* __restrict__ be,
                       const int* __restrict__ src, const int* __restrict__ dst,
                       const float* __restrict__ h, float* __restrict__ agg) {
  __shared__ float sWe[16 * 128];
  __shared__ float sbe[128];
  int tid = threadIdx.x;
  for (int i = tid; i < 2048; i += 256) sWe[i] = We[i];
  if (tid < 128) sbe[tid] = be[tid];
  __syncthreads();
  int c = tid & 127;
  int half = tid >> 7;
  int stride = gridDim.x * 2;
  for (int e = blockIdx.x * 2 + half; e < E; e += stride) {
    int s = src[e], d = dst[e];
    const float4* ea4 = reinterpret_cast<const float4*>(edge_attr) + e * 4;
    float4 a0 = ea4[0], a1 = ea4[1], a2 = ea4[2], a3 = ea4[3];
    float ev = sbe[c];
    ev += a0.x * sWe[c]        + a0.y * sWe[128 + c]  + a0.z * sWe[256 + c]  + a0.w * sWe[384 + c];
    ev += a1.x * sWe[512 + c]  + a1.y * sWe[640 + c]  + a1.z * sWe[768 + c]  + a1.w * sWe[896 + c];
    ev += a2.x * sWe[1024 + c] + a2.y * sWe[1152 + c] + a2.z * sWe[1280 + c] + a2.w * sWe[1408 + c];
    ev += a3.x * sWe[1536 + c] + a3.y * sWe[1664 + c] + a3.z * sWe[1792 + c] + a3.w * sWe[1920 + c];
    float m = h[s * 128 + c] + ev;
    if (m > 0.f) atomicAdd(&agg[d * 128 + c], m);
  }
}

// ---------------------------------------------------------------------------
// Generic fp32 GEMM: C[M x ldw], 32-row x 128-col tile per block, blockIdx.y
// picks the 128-col chunk. MODE 0: A = A1; MODE 1: A = A1 + A2 (both [M][K]).
// Optional bias[col], optional per-row gathered bias rowbias[batch[r]][col],
// optional relu. ldc == ldw for all uses.
template<int K, int MODE, bool HAS_BIAS, bool HAS_ROWBIAS, bool RELU>
__global__ __launch_bounds__(256) void k_gemm(
    const float* __restrict__ A1, const float* __restrict__ A2,
    const float* __restrict__ W, int ldw,
    const float* __restrict__ bias,
    const float* __restrict__ rowbias, const int* __restrict__ batch,
    float* __restrict__ C, int M) {
  __shared__ float As[32 * K];
  constexpr int K4 = K / 4;
  int tid = threadIdx.x;
  int m0 = blockIdx.x * 32;
  // stage A tile (zero-pad rows past M)
#pragma unroll
  for (int it = 0; it < K / 32; ++it) {
    int e4 = it * 256 + tid;
    int r = e4 / K4;
    int k4 = e4 % K4;
    int gr = m0 + r;
    float4 v = make_float4(0.f, 0.f, 0.f, 0.f);
    if (gr < M) {
      if (MODE == 1) {
        float4 va = reinterpret_cast<const float4*>(A1)[(long long)gr * K4 + k4];
        float4 vb = reinterpret_cast<const float4*>(A2)[(long long)gr * K4 + k4];
        v = make_float4(va.x + vb.x, va.y + vb.y, va.z + vb.z, va.w + vb.w);
      } else {
        v = reinterpret_cast<const float4*>(A1)[(long long)gr * K4 + k4];
      }
    }
    reinterpret_cast<float4*>(As)[e4] = v;
  }
  __syncthreads();

  int cg = tid & 31;        // column group: 4 cols each
  int rg = tid >> 5;        // 0..7 row group; rows rg, rg+8, rg+16, rg+24
  int col = blockIdx.y * 128 + cg * 4;
  float4 acc[4];
#pragma unroll
  for (int j = 0; j < 4; ++j) acc[j] = make_float4(0.f, 0.f, 0.f, 0.f);
  const float4* W4 = reinterpret_cast<const float4*>(W);
  const float4* As4 = reinterpret_cast<const float4*>(As);
#pragma unroll 8
  for (int k = 0; k < K; k += 4) {
    float4 w0 = W4[((k + 0) * ldw + col) >> 2];
    float4 w1 = W4[((k + 1) * ldw + col) >> 2];
    float4 w2 = W4[((k + 2) * ldw + col) >> 2];
    float4 w3 = W4[((k + 3) * ldw + col) >> 2];
#pragma unroll
    for (int j = 0; j < 4; ++j) {
      float4 a = As4[(rg + j * 8) * K4 + (k >> 2)];
      acc[j].x += a.x * w0.x + a.y * w1.x + a.z * w2.x + a.w * w3.x;
      acc[j].y += a.x * w0.y + a.y * w1.y + a.z * w2.y + a.w * w3.y;
      acc[j].z += a.x * w0.z + a.y * w1.z + a.z * w2.z + a.w * w3.z;
      acc[j].w += a.x * w0.w + a.y * w1.w + a.z * w2.w + a.w * w3.w;
    }
  }
  float4 bb = make_float4(0.f, 0.f, 0.f, 0.f);
  if (HAS_BIAS) bb = reinterpret_cast<const float4*>(bias)[blockIdx.y * 32 + cg];
#pragma unroll
  for (int j = 0; j < 4; ++j) {
    int gr = m0 + rg + j * 8;
    if (gr < M) {
      float4 v = acc[j];
      v.x += bb.x; v.y += bb.y; v.z += bb.z; v.w += bb.w;
      if (HAS_ROWBIAS) {
        int b = batch[gr];
        float4 rb = reinterpret_cast<const float4*>(rowbias)[((long long)b * ldw + col) >> 2];
        v.x += rb.x; v.y += rb.y; v.z += rb.z; v.w += rb.w;
      }
      if (RELU) {
        v.x = fmaxf(v.x, 0.f); v.y = fmaxf(v.y, 0.f);
        v.z = fmaxf(v.z, 0.f); v.w = fmaxf(v.w, 0.f);
      }
      reinterpret_cast<float4*>(C)[((long long)gr * ldw + col) >> 2] = v;
    }
  }
}

// ---------------------------------------------------------------------------
// Column sum / sumsq over M rows of X[M][NC] -> stats[0:NC]=sum, stats[NC:2NC]=sumsq
template<int NC>
__global__ void k_stats(const float* __restrict__ X, int M, float* __restrict__ stats) {
  constexpr int RP = 256 / NC;  // rows processed in parallel per block
  int c = threadIdx.x % NC;
  int rsub = threadIdx.x / NC;
  float s = 0.f, s2 = 0.f;
  for (int r = blockIdx.x * RP + rsub; r < M; r += gridDim.x * RP) {
    float v = X[(long long)r * NC + c];
    s += v; s2 += v * v;
  }
  if (RP > 1) {
    __shared__ float ls[512];
    ls[threadIdx.x] = s; ls[256 + threadIdx.x] = s2;
    __syncthreads();
    if (rsub == 0) {
#pragma unroll
      for (int j = 1; j < RP; ++j) { s += ls[j * NC + c]; s2 += ls[256 + j * NC + c]; }
    }
  }
  if (rsub == 0) { atomicAdd(&stats[c], s); atomicAdd(&stats[NC + c], s2); }
}

// out = relu(bn(X)) elementwise, stats precomputed
template<int NC>
__global__ void k_bnapply(const float* __restrict__ X, const float* __restrict__ stats,
                          const float* __restrict__ gam, const float* __restrict__ beta,
                          float* __restrict__ out, int total, float invM) {
  int idx = blockIdx.x * 256 + threadIdx.x;
  if (idx >= total) return;
  int c = idx & (NC - 1);
  float mean = stats[c] * invM;
  float var = stats[NC + c] * invM - mean * mean;
  float v = (X[idx] - mean) * rsqrtf(var + EPS) * gam[c] + beta[c];
  out[idx] = fmaxf(v, 0.f);
}

// pooled[g] += relu(bn(z2[r])) for rows r with batch[r]==g.
// batch is sorted: run-length compress atomics within each block's row range.
__global__ void k_pool(const float* __restrict__ z2, const float* __restrict__ stats,
                       const float* __restrict__ gam, const float* __restrict__ beta,
                       const int* __restrict__ batch, float* __restrict__ pooled) {
  int c = threadIdx.x;  // 256 cols
  const float invM = 1.f / (float)N;
  float mean = stats[c] * invM;
  float var = stats[256 + c] * invM - mean * mean;
  float scale = rsqrtf(var + EPS) * gam[c];
  float shift = beta[c] - mean * scale;
  int r0 = blockIdx.x * 128;
  int r1 = min(r0 + 128, N);
  if (r0 >= N) return;
  int curg = batch[r0];
  float acc = 0.f;
  for (int r = r0; r < r1; ++r) {
    int gb = batch[r];
    float v = fmaxf(z2[(long long)r * 256 + c] * scale + shift, 0.f);
    if (gb != curg) { atomicAdd(&pooled[curg * 256 + c], acc); acc = v; curg = gb; }
    else acc += v;
  }
  atomicAdd(&pooled[curg * 256 + c], acc);
}

// vn = relu(bn(zvn)); also write into hg concat buffer at layer offset
__global__ void k_vnapply(const float* __restrict__ zvn, const float* __restrict__ stats,
                          const float* __restrict__ gam, const float* __restrict__ beta,
                          float* __restrict__ vn, float* __restrict__ hgbuf, int layer) {
  int idx = blockIdx.x * 256 + threadIdx.x;  // G*H = 65536
  int c = idx & 127;
  int g = idx >> 7;
  const float invM = 1.f / (float)G;
  float mean = stats[c] * invM;
  float var = stats[128 + c] * invM - mean * mean;
  float v = fmaxf((zvn[idx] - mean) * rsqrtf(var + EPS) * gam[c] + beta[c], 0.f);
  vn[idx] = v;
  hgbuf[g * 384 + layer * 128 + c] = v;
}

// out[g] = hg2[g] @ pred_W2 + b2   (one wave per graph)
__global__ void k_pred2(const float* __restrict__ hg2, const float* __restrict__ W2,
                        const float* __restrict__ b2, float* __restrict__ out) {
  int g = blockIdx.x;
  int lane = threadIdx.x;
  float s = 0.f;
  for (int k = lane; k < 384; k += 64) s += hg2[g * 384 + k] * W2[k];
  for (int off = 32; off; off >>= 1) s += __shfl_down(s, off);
  if (lane == 0) out[g] = s + b2[0];
}

// ---------------------------------------------------------------------------
extern "C" void kernel_launch(void* const* d_in, const int* in_sizes, int n_in,
                              void* d_out, int out_size, void* d_ws, size_t ws_size,
                              hipStream_t stream) {
  const float* x         = (const float*)d_in[0];
  const float* edge_attr = (const float*)d_in[1];
  const float* atom_W    = (const float*)d_in[2];
  const float* atom_b    = (const float*)d_in[3];
  const float* vn_emb    = (const float*)d_in[4];
  const float* conv_We   = (const float*)d_in[5];
  const float* conv_be   = (const float*)d_in[6];
  const float* conv_W    = (const float*)d_in[7];
  const float* conv_b    = (const float*)d_in[8];
  const float* conv_g    = (const float*)d_in[9];
  const float* conv_beta = (const float*)d_in[10];
  const float* vn1_W     = (const float*)d_in[11];
  const float* vn1_b     = (const float*)d_in[12];
  const float* vn1_g     = (const float*)d_in[13];
  const float* vn1_beta  = (const float*)d_in[14];
  const float* vn2_W     = (const float*)d_in[15];
  const float* vn2_b     = (const float*)d_in[16];
  const float* vn2_g     = (const float*)d_in[17];
  const float* vn2_beta  = (const float*)d_in[18];
  const float* pred_W1   = (const float*)d_in[19];
  const float* pred_b1   = (const float*)d_in[20];
  const float* pred_W2   = (const float*)d_in[21];
  const float* pred_b2   = (const float*)d_in[22];
  const int*   eidx      = (const int*)d_in[23];
  const int*   batch     = (const int*)d_in[24];
  const int* src = eidx;
  const int* dst = eidx + E;

  // Workspace layout (floats). Total ~20.1M floats = ~80.3 MB.
  float* ws    = (float*)d_ws;
  float* h     = ws;                         // N*128
  float* bufB  = ws + NH;                    // N*256 (agg | z, later z2)
  float* agg   = bufB;                       // N*128
  float* z     = bufB + NH;                  // N*128
  float* z2    = bufB;                       // N*256 (aliases agg+z after both dead)
  float* U     = ws + 3 * NH;                // G*256
  float* pooled= U + G * 256;                // G*256
  float* zvn   = pooled + G * 256;           // G*128
  float* vn    = zvn + G * 128;              // G*128
  float* hgbuf = vn + G * 128;               // G*384
  float* hg2   = hgbuf + G * 384;            // G*384
  float* stats = hg2 + G * 384;              // 512

  dim3 b256(256);

  k_init_vn<<<G * 128 / 256, b256, 0, stream>>>(vn_emb, vn);
  // h = x @ atom_W + atom_b
  k_gemm<128, 0, true, false, false><<<dim3(1563, 1), b256, 0, stream>>>(
      x, nullptr, atom_W, 128, atom_b, nullptr, nullptr, h, N);

  for (int i = 0; i < 3; ++i) {
    hipMemsetAsync(agg, 0, (size_t)NH * 4, stream);
    k_addvn<<<N * 32 / 256, b256, 0, stream>>>(h, vn, batch);
    k_edge<<<2048, b256, 0, stream>>>(edge_attr, conv_We + i * 2048, conv_be + i * 128,
                                      src, dst, h, agg);
    // z = (h + agg) @ conv_W[i] + conv_b[i]
    k_gemm<128, 1, true, false, false><<<dim3(1563, 1), b256, 0, stream>>>(
        h, agg, conv_W + i * 128 * 128, 128, conv_b + i * 128, nullptr, nullptr, z, N);
    hipMemsetAsync(stats, 0, 2048, stream);
    k_stats<128><<<256, b256, 0, stream>>>(z, N, stats);
    // h = relu(bn(z))
    k_bnapply<128><<<N * 128 / 256, b256, 0, stream>>>(
        z, stats, conv_g + i * 128, conv_beta + i * 128, h, N * 128, 1.f / (float)N);
    // U = vn @ vn1_W[i][:128,:] + vn1_b[i]   (only 512 distinct rows of vn[batch])
    k_gemm<128, 0, true, false, false><<<dim3(16, 2), b256, 0, stream>>>(
        vn, nullptr, vn1_W + i * 256 * 256, 256, vn1_b + i * 256, nullptr, nullptr, U, G);
    // z2 = h @ vn1_W[i][128:,:] + U[batch]
    k_gemm<128, 0, false, true, false><<<dim3(1563, 2), b256, 0, stream>>>(
        h, nullptr, vn1_W + i * 256 * 256 + 128 * 256, 256, nullptr, U, batch, z2, N);
    hipMemsetAsync(stats, 0, 2048, stream);
    k_stats<256><<<256, b256, 0, stream>>>(z2, N, stats);
    hipMemsetAsync(pooled, 0, (size_t)G * 256 * 4, stream);
    k_pool<<<(N + 127) / 128, b256, 0, stream>>>(
        z2, stats, vn1_g + i * 256, vn1_beta + i * 256, batch, pooled);
    // zvn = pooled @ vn2_W[i] + vn2_b[i]
    k_gemm<256, 0, true, false, false><<<dim3(16, 1), b256, 0, stream>>>(
        pooled, nullptr, vn2_W + i * 256 * 128, 128, vn2_b + i * 128, nullptr, nullptr, zvn, G);
    hipMemsetAsync(stats, 0, 2048, stream);
    k_stats<128><<<16, b256, 0, stream>>>(zvn, G, stats);
    k_vnapply<<<G * 128 / 256, b256, 0, stream>>>(
        zvn, stats, vn2_g + i * 128, vn2_beta + i * 128, vn, hgbuf, i);
  }
  // hg2 = relu(hgbuf @ pred_W1 + pred_b1)
  k_gemm<384, 0, true, false, true><<<dim3(16, 3), b256, 0, stream>>>(
      hgbuf, nullptr, pred_W1, 384, pred_b1, nullptr, nullptr, hg2, G);
  k_pred2<<<G, 64, 0, stream>>>(hg2, pred_W2, pred_b2, (float*)d_out);
}

// Round 3
// 1807.861 us; speedup vs baseline: 1.2981x; 1.2981x over previous
//
#include <hip/hip_runtime.h>

// Problem constants (fixed by the reference)
constexpr int N = 50000;
constexpr int E = 800000;
constexpr int G = 512;
constexpr int H = 128;
constexpr long long NH = (long long)N * H;   // 6,400,000 floats
constexpr float EPS = 1e-5f;
constexpr int NB_SCAN = 196;                 // ceil(50000/256)

// ---------------------------------------------------------------------------
// vn[g][c] = vn_emb[c]
__global__ void k_init_vn(const float* __restrict__ vn_emb, float* __restrict__ vn) {
  int idx = blockIdx.x * 256 + threadIdx.x;   // G*H = 65536 exactly
  vn[idx] = vn_emb[idx & 127];
}

// h[r][:] += vn[batch[r]][:]  (float4-vectorized, grid covers N*32 float4s exactly)
__global__ void k_addvn(float* __restrict__ h, const float* __restrict__ vn,
                        const int* __restrict__ batch) {
  int i4 = blockIdx.x * 256 + threadIdx.x;
  int r = i4 >> 5;
  int b = batch[r];
  float4 hv = reinterpret_cast<float4*>(h)[i4];
  float4 vv = reinterpret_cast<const float4*>(vn)[(b << 5) + (i4 & 31)];
  hv.x += vv.x; hv.y += vv.y; hv.z += vv.z; hv.w += vv.w;
  reinterpret_cast<float4*>(h)[i4] = hv;
}

// ---------------------------------------------------------------------------
// CSR build: histogram -> 2-level exclusive scan -> scatter (dst-sorted int2(src,eid))
__global__ void k_hist(const int* __restrict__ dst, int* __restrict__ cnt) {
  int e = blockIdx.x * 256 + threadIdx.x;   // grid covers E exactly
  atomicAdd(&cnt[dst[e]], 1);
}

__global__ void k_scan_block(const int* __restrict__ cnt, int* __restrict__ off,
                             int* __restrict__ bsum) {
  __shared__ int s[256];
  int idx = blockIdx.x * 256 + threadIdx.x;
  int v = (idx < N) ? cnt[idx] : 0;
  s[threadIdx.x] = v;
  __syncthreads();
  for (int o = 1; o < 256; o <<= 1) {
    int t = (threadIdx.x >= o) ? s[threadIdx.x - o] : 0;
    __syncthreads();
    s[threadIdx.x] += t;
    __syncthreads();
  }
  if (idx < N) off[idx + 1] = s[threadIdx.x];
  if (threadIdx.x == 255) bsum[blockIdx.x] = s[255];
  if (idx == 0) off[0] = 0;
}

__global__ void k_scan_bsum(int* __restrict__ bsum) {   // single block
  __shared__ int s[256];
  int v = (threadIdx.x < NB_SCAN) ? bsum[threadIdx.x] : 0;
  s[threadIdx.x] = v;
  __syncthreads();
  for (int o = 1; o < 256; o <<= 1) {
    int t = (threadIdx.x >= o) ? s[threadIdx.x - o] : 0;
    __syncthreads();
    s[threadIdx.x] += t;
    __syncthreads();
  }
  if (threadIdx.x < NB_SCAN) bsum[threadIdx.x] = s[threadIdx.x];  // inclusive
}

__global__ void k_scan_add(int* __restrict__ off, const int* __restrict__ bsum) {
  int idx = blockIdx.x * 256 + threadIdx.x;
  if (idx < N && blockIdx.x > 0) off[idx + 1] += bsum[blockIdx.x - 1];
}

__global__ void k_scatter(const int* __restrict__ src, const int* __restrict__ dst,
                          const int* __restrict__ off, int* __restrict__ cur,
                          int2* __restrict__ sE) {
  int e = blockIdx.x * 256 + threadIdx.x;   // grid covers E exactly
  int d = dst[e];
  int p = off[d] + atomicAdd(&cur[d], 1);
  sE[p] = make_int2(src[e], e);
}

// ---------------------------------------------------------------------------
// CSR aggregation, atomic-free. One 64-lane wave per dst node (2 cols/lane).
// out[d] = h[d] + sum_{e in in(d)} relu(h[src[e]] + edge_attr[e] @ We + be)
__global__ __launch_bounds__(256) void k_agg(
    const float* __restrict__ edge_attr, const float* __restrict__ We,
    const float* __restrict__ be, const int* __restrict__ off,
    const int2* __restrict__ sE, const float* __restrict__ h,
    float* __restrict__ out) {
  __shared__ float sWe[16 * 128];
  __shared__ float sbe[128];
  int tid = threadIdx.x;
  for (int i = tid; i < 2048; i += 256) sWe[i] = We[i];
  if (tid < 128) sbe[tid] = be[tid];
  __syncthreads();
  int w = tid >> 6;       // wave id in block: 4 nodes per block
  int lane = tid & 63;
  int d = blockIdx.x * 4 + w;   // grid = 12500 -> covers N exactly
  if (d >= N) return;
  int j0 = off[d], j1 = off[d + 1];
  float a0 = 0.f, a1 = 0.f;
  for (int j = j0; j < j1; ++j) {
    int2 se = sE[j];                                   // broadcast load
    const float4* ea4 = reinterpret_cast<const float4*>(edge_attr) + se.y * 4;
    float qa[16];
    *reinterpret_cast<float4*>(qa)      = ea4[0];
    *reinterpret_cast<float4*>(qa + 4)  = ea4[1];
    *reinterpret_cast<float4*>(qa + 8)  = ea4[2];
    *reinterpret_cast<float4*>(qa + 12) = ea4[3];
    float ev0 = sbe[lane], ev1 = sbe[lane + 64];
#pragma unroll
    for (int k = 0; k < 16; ++k) {
      ev0 += qa[k] * sWe[k * 128 + lane];
      ev1 += qa[k] * sWe[k * 128 + 64 + lane];
    }
    const float* hs = h + (long long)se.x * 128;
    a0 += fmaxf(hs[lane] + ev0, 0.f);
    a1 += fmaxf(hs[64 + lane] + ev1, 0.f);
  }
  const float* hd = h + (long long)d * 128;
  out[(long long)d * 128 + lane]      = hd[lane] + a0;
  out[(long long)d * 128 + 64 + lane] = hd[64 + lane] + a1;
}

// ---------------------------------------------------------------------------
// Generic fp32 GEMM: C[M x ldw], 32-row x 128-col tile per block, blockIdx.y
// picks the 128-col chunk. Optional bias[col], optional per-row gathered bias
// rowbias[batch[r]][col], optional relu. ldc == ldw for all uses.
template<int K, bool HAS_BIAS, bool HAS_ROWBIAS, bool RELU>
__global__ __launch_bounds__(256) void k_gemm(
    const float* __restrict__ A1,
    const float* __restrict__ W, int ldw,
    const float* __restrict__ bias,
    const float* __restrict__ rowbias, const int* __restrict__ batch,
    float* __restrict__ C, int M) {
  __shared__ float As[32 * K];
  constexpr int K4 = K / 4;
  int tid = threadIdx.x;
  int m0 = blockIdx.x * 32;
  // stage A tile (zero-pad rows past M)
#pragma unroll
  for (int it = 0; it < K / 32; ++it) {
    int e4 = it * 256 + tid;
    int r = e4 / K4;
    int k4 = e4 % K4;
    int gr = m0 + r;
    float4 v = make_float4(0.f, 0.f, 0.f, 0.f);
    if (gr < M) v = reinterpret_cast<const float4*>(A1)[(long long)gr * K4 + k4];
    reinterpret_cast<float4*>(As)[e4] = v;
  }
  __syncthreads();

  int cg = tid & 31;        // column group: 4 cols each
  int rg = tid >> 5;        // 0..7 row group; rows rg, rg+8, rg+16, rg+24
  int col = blockIdx.y * 128 + cg * 4;
  float4 acc[4];
#pragma unroll
  for (int j = 0; j < 4; ++j) acc[j] = make_float4(0.f, 0.f, 0.f, 0.f);
  const float4* W4 = reinterpret_cast<const float4*>(W);
  const float4* As4 = reinterpret_cast<const float4*>(As);
#pragma unroll 8
  for (int k = 0; k < K; k += 4) {
    float4 w0 = W4[((k + 0) * ldw + col) >> 2];
    float4 w1 = W4[((k + 1) * ldw + col) >> 2];
    float4 w2 = W4[((k + 2) * ldw + col) >> 2];
    float4 w3 = W4[((k + 3) * ldw + col) >> 2];
#pragma unroll
    for (int j = 0; j < 4; ++j) {
      float4 a = As4[(rg + j * 8) * K4 + (k >> 2)];
      acc[j].x += a.x * w0.x + a.y * w1.x + a.z * w2.x + a.w * w3.x;
      acc[j].y += a.x * w0.y + a.y * w1.y + a.z * w2.y + a.w * w3.y;
      acc[j].z += a.x * w0.z + a.y * w1.z + a.z * w2.z + a.w * w3.z;
      acc[j].w += a.x * w0.w + a.y * w1.w + a.z * w2.w + a.w * w3.w;
    }
  }
  float4 bb = make_float4(0.f, 0.f, 0.f, 0.f);
  if (HAS_BIAS) bb = reinterpret_cast<const float4*>(bias)[blockIdx.y * 32 + cg];
#pragma unroll
  for (int j = 0; j < 4; ++j) {
    int gr = m0 + rg + j * 8;
    if (gr < M) {
      float4 v = acc[j];
      v.x += bb.x; v.y += bb.y; v.z += bb.z; v.w += bb.w;
      if (HAS_ROWBIAS) {
        int b = batch[gr];
        float4 rb = reinterpret_cast<const float4*>(rowbias)[((long long)b * ldw + col) >> 2];
        v.x += rb.x; v.y += rb.y; v.z += rb.z; v.w += rb.w;
      }
      if (RELU) {
        v.x = fmaxf(v.x, 0.f); v.y = fmaxf(v.y, 0.f);
        v.z = fmaxf(v.z, 0.f); v.w = fmaxf(v.w, 0.f);
      }
      reinterpret_cast<float4*>(C)[((long long)gr * ldw + col) >> 2] = v;
    }
  }
}

// ---------------------------------------------------------------------------
// Column sum / sumsq over M rows of X[M][NC] -> stats[0:NC]=sum, stats[NC:2NC]=sumsq
template<int NC>
__global__ void k_stats(const float* __restrict__ X, int M, float* __restrict__ stats) {
  constexpr int RP = 256 / NC;  // rows processed in parallel per block
  int c = threadIdx.x % NC;
  int rsub = threadIdx.x / NC;
  float s = 0.f, s2 = 0.f;
  for (int r = blockIdx.x * RP + rsub; r < M; r += gridDim.x * RP) {
    float v = X[(long long)r * NC + c];
    s += v; s2 += v * v;
  }
  if (RP > 1) {
    __shared__ float ls[512];
    ls[threadIdx.x] = s; ls[256 + threadIdx.x] = s2;
    __syncthreads();
    if (rsub == 0) {
#pragma unroll
      for (int j = 1; j < RP; ++j) { s += ls[j * NC + c]; s2 += ls[256 + j * NC + c]; }
    }
  }
  if (rsub == 0) { atomicAdd(&stats[c], s); atomicAdd(&stats[NC + c], s2); }
}

// out = relu(bn(X)) elementwise, stats precomputed
template<int NC>
__global__ void k_bnapply(const float* __restrict__ X, const float* __restrict__ stats,
                          const float* __restrict__ gam, const float* __restrict__ beta,
                          float* __restrict__ out, int total, float invM) {
  int idx = blockIdx.x * 256 + threadIdx.x;
  if (idx >= total) return;
  int c = idx & (NC - 1);
  float mean = stats[c] * invM;
  float var = stats[NC + c] * invM - mean * mean;
  float v = (X[idx] - mean) * rsqrtf(var + EPS) * gam[c] + beta[c];
  out[idx] = fmaxf(v, 0.f);
}

// pooled[g] += relu(bn(z2[r])) for rows r with batch[r]==g.
// batch is sorted: run-length compress atomics within each block's row range.
__global__ void k_pool(const float* __restrict__ z2, const float* __restrict__ stats,
                       const float* __restrict__ gam, const float* __restrict__ beta,
                       const int* __restrict__ batch, float* __restrict__ pooled) {
  int c = threadIdx.x;  // 256 cols
  const float invM = 1.f / (float)N;
  float mean = stats[c] * invM;
  float var = stats[256 + c] * invM - mean * mean;
  float scale = rsqrtf(var + EPS) * gam[c];
  float shift = beta[c] - mean * scale;
  int r0 = blockIdx.x * 128;
  int r1 = min(r0 + 128, N);
  if (r0 >= N) return;
  int curg = batch[r0];
  float acc = 0.f;
  for (int r = r0; r < r1; ++r) {
    int gb = batch[r];
    float v = fmaxf(z2[(long long)r * 256 + c] * scale + shift, 0.f);
    if (gb != curg) { atomicAdd(&pooled[curg * 256 + c], acc); acc = v; curg = gb; }
    else acc += v;
  }
  atomicAdd(&pooled[curg * 256 + c], acc);
}

// vn = relu(bn(zvn)); also write into hg concat buffer at layer offset
__global__ void k_vnapply(const float* __restrict__ zvn, const float* __restrict__ stats,
                          const float* __restrict__ gam, const float* __restrict__ beta,
                          float* __restrict__ vn, float* __restrict__ hgbuf, int layer) {
  int idx = blockIdx.x * 256 + threadIdx.x;  // G*H = 65536
  int c = idx & 127;
  int g = idx >> 7;
  const float invM = 1.f / (float)G;
  float mean = stats[c] * invM;
  float var = stats[128 + c] * invM - mean * mean;
  float v = fmaxf((zvn[idx] - mean) * rsqrtf(var + EPS) * gam[c] + beta[c], 0.f);
  vn[idx] = v;
  hgbuf[g * 384 + layer * 128 + c] = v;
}

// out[g] = hg2[g] @ pred_W2 + b2   (one wave per graph)
__global__ void k_pred2(const float* __restrict__ hg2, const float* __restrict__ W2,
                        const float* __restrict__ b2, float* __restrict__ out) {
  int g = blockIdx.x;
  int lane = threadIdx.x;
  float s = 0.f;
  for (int k = lane; k < 384; k += 64) s += hg2[g * 384 + k] * W2[k];
  for (int off = 32; off; off >>= 1) s += __shfl_down(s, off);
  if (lane == 0) out[g] = s + b2[0];
}

// ---------------------------------------------------------------------------
extern "C" void kernel_launch(void* const* d_in, const int* in_sizes, int n_in,
                              void* d_out, int out_size, void* d_ws, size_t ws_size,
                              hipStream_t stream) {
  const float* x         = (const float*)d_in[0];
  const float* edge_attr = (const float*)d_in[1];
  const float* atom_W    = (const float*)d_in[2];
  const float* atom_b    = (const float*)d_in[3];
  const float* vn_emb    = (const float*)d_in[4];
  const float* conv_We   = (const float*)d_in[5];
  const float* conv_be   = (const float*)d_in[6];
  const float* conv_W    = (const float*)d_in[7];
  const float* conv_b    = (const float*)d_in[8];
  const float* conv_g    = (const float*)d_in[9];
  const float* conv_beta = (const float*)d_in[10];
  const float* vn1_W     = (const float*)d_in[11];
  const float* vn1_b     = (const float*)d_in[12];
  const float* vn1_g     = (const float*)d_in[13];
  const float* vn1_beta  = (const float*)d_in[14];
  const float* vn2_W     = (const float*)d_in[15];
  const float* vn2_b     = (const float*)d_in[16];
  const float* vn2_g     = (const float*)d_in[17];
  const float* vn2_beta  = (const float*)d_in[18];
  const float* pred_W1   = (const float*)d_in[19];
  const float* pred_b1   = (const float*)d_in[20];
  const float* pred_W2   = (const float*)d_in[21];
  const float* pred_b2   = (const float*)d_in[22];
  const int*   eidx      = (const int*)d_in[23];
  const int*   batch     = (const int*)d_in[24];
  const int* src = eidx;
  const int* dst = eidx + E;

  // Workspace layout. Floats: h | bufB(N*256) | small block. Ints after: off, sE.
  float* ws    = (float*)d_ws;
  float* h     = ws;                         // N*128
  float* bufB  = ws + NH;                    // N*256 (hpa | z, later z2)
  float* hpa   = bufB;                       // N*128 (h + agg, conv GEMM input)
  float* z     = bufB + NH;                  // N*128
  float* z2    = bufB;                       // N*256
  float* U     = ws + 3 * NH;                // G*256
  float* pooled= U + G * 256;                // G*256
  float* zvn   = pooled + G * 256;           // G*128
  float* vn    = zvn + G * 128;              // G*128
  float* hgbuf = vn + G * 128;               // G*384
  float* hg2   = hgbuf + G * 384;            // G*384
  float* stats = hg2 + G * 384;              // 512
  // persistent CSR (must not alias bufB):
  int*  intb   = (int*)(stats + 512);
  int*  off    = intb;                       // N+1 (padded to 50002)
  int2* sE     = (int2*)(intb + 50002);      // E int2s
  // build-time temporaries (dead before first k_agg) alias bufB:
  int* cnt  = (int*)bufB;                    // N
  int* cur  = cnt + N;                       // N
  int* bsum = cur + N;                       // NB_SCAN

  dim3 b256(256);

  // ---- CSR build (once; edge_index identical across layers) ----
  hipMemsetAsync(cnt, 0, (size_t)N * 4, stream);
  hipMemsetAsync(cur, 0, (size_t)N * 4, stream);
  k_hist<<<E / 256, b256, 0, stream>>>(dst, cnt);
  k_scan_block<<<NB_SCAN, b256, 0, stream>>>(cnt, off, bsum);
  k_scan_bsum<<<1, b256, 0, stream>>>(bsum);
  k_scan_add<<<NB_SCAN, b256, 0, stream>>>(off, bsum);
  k_scatter<<<E / 256, b256, 0, stream>>>(src, dst, off, cur, sE);

  k_init_vn<<<G * 128 / 256, b256, 0, stream>>>(vn_emb, vn);
  // h = x @ atom_W + atom_b
  k_gemm<128, true, false, false><<<dim3(1563, 1), b256, 0, stream>>>(
      x, atom_W, 128, atom_b, nullptr, nullptr, h, N);

  for (int i = 0; i < 3; ++i) {
    k_addvn<<<N * 32 / 256, b256, 0, stream>>>(h, vn, batch);
    // hpa = h + sum_in relu(h[src] + ea@We + be)   (atomic-free CSR gather)
    k_agg<<<12500, b256, 0, stream>>>(edge_attr, conv_We + i * 2048, conv_be + i * 128,
                                      off, sE, h, hpa);
    // z = hpa @ conv_W[i] + conv_b[i]
    k_gemm<128, true, false, false><<<dim3(1563, 1), b256, 0, stream>>>(
        hpa, conv_W + i * 128 * 128, 128, conv_b + i * 128, nullptr, nullptr, z, N);
    hipMemsetAsync(stats, 0, 2048, stream);
    k_stats<128><<<256, b256, 0, stream>>>(z, N, stats);
    // h = relu(bn(z))
    k_bnapply<128><<<N * 128 / 256, b256, 0, stream>>>(
        z, stats, conv_g + i * 128, conv_beta + i * 128, h, N * 128, 1.f / (float)N);
    // U = vn @ vn1_W[i][:128,:] + vn1_b[i]   (only 512 distinct rows of vn[batch])
    k_gemm<128, true, false, false><<<dim3(16, 2), b256, 0, stream>>>(
        vn, vn1_W + i * 256 * 256, 256, vn1_b + i * 256, nullptr, nullptr, U, G);
    // z2 = h @ vn1_W[i][128:,:] + U[batch]
    k_gemm<128, false, true, false><<<dim3(1563, 2), b256, 0, stream>>>(
        h, vn1_W + i * 256 * 256 + 128 * 256, 256, nullptr, U, batch, z2, N);
    hipMemsetAsync(stats, 0, 2048, stream);
    k_stats<256><<<256, b256, 0, stream>>>(z2, N, stats);
    hipMemsetAsync(pooled, 0, (size_t)G * 256 * 4, stream);
    k_pool<<<(N + 127) / 128, b256, 0, stream>>>(
        z2, stats, vn1_g + i * 256, vn1_beta + i * 256, batch, pooled);
    // zvn = pooled @ vn2_W[i] + vn2_b[i]
    k_gemm<256, true, false, false><<<dim3(16, 1), b256, 0, stream>>>(
        pooled, vn2_W + i * 256 * 128, 128, vn2_b + i * 128, nullptr, nullptr, zvn, G);
    hipMemsetAsync(stats, 0, 2048, stream);
    k_stats<128><<<16, b256, 0, stream>>>(zvn, G, stats);
    k_vnapply<<<G * 128 / 256, b256, 0, stream>>>(
        zvn, stats, vn2_g + i * 128, vn2_beta + i * 128, vn, hgbuf, i);
  }
  // hg2 = relu(hgbuf @ pred_W1 + pred_b1)
  k_gemm<384, true, false, true><<<dim3(16, 3), b256, 0, stream>>>(
      hgbuf, pred_W1, 384, pred_b1, nullptr, nullptr, hg2, G);
  k_pred2<<<G, 64, 0, stream>>>(hg2, pred_W2, pred_b2, (float*)d_out);
}

// Round 4
// 1742.302 us; speedup vs baseline: 1.3469x; 1.0376x over previous
//
#include <hip/hip_runtime.h>
#include <hip/hip_fp16.h>

// Problem constants (fixed by the reference)
constexpr int N = 50000;
constexpr int E = 800000;
constexpr int G = 512;
constexpr int H = 128;
constexpr long long NH = (long long)N * H;   // 6,400,000 elements
constexpr float EPS = 1e-5f;
constexpr int NB_SCAN = 196;                 // ceil(50000/256)

typedef _Float16 f16x8 __attribute__((ext_vector_type(8)));
typedef float f32x4 __attribute__((ext_vector_type(4)));

// ---------------------------------------------------------------------------
// vn[g][c] = vn_emb[c]
__global__ void k_init_vn(const float* __restrict__ vn_emb, float* __restrict__ vn) {
  int idx = blockIdx.x * 256 + threadIdx.x;   // G*H = 65536 exactly
  vn[idx] = vn_emb[idx & 127];
}

// fp32 -> fp16 bulk convert (float4 -> half2 x2), grid covers n4 exactly
__global__ void k_tof16(const float* __restrict__ in, __half* __restrict__ out, int n4) {
  int i = blockIdx.x * 256 + threadIdx.x;
  if (i >= n4) return;
  float4 v = reinterpret_cast<const float4*>(in)[i];
  __half2* o = reinterpret_cast<__half2*>(out);
  o[i * 2]     = __floats2half2_rn(v.x, v.y);
  o[i * 2 + 1] = __floats2half2_rn(v.z, v.w);
}

// Wt[c][k] = (half) W[(row0+k)*ldw + c], K=128 fixed; one layer per blockIdx.y
__global__ void k_wt(const float* __restrict__ W, __half* __restrict__ Wt,
                     int ldw, int row0, int cols, long long wstride, int wtstride) {
  const float* Wl = W + (long long)blockIdx.y * wstride;
  __half* Wtl = Wt + (long long)blockIdx.y * wtstride;
  int idx = blockIdx.x * 256 + threadIdx.x;   // cols*128, exact multiple of 256
  int k = idx & 127, c = idx >> 7;
  Wtl[c * 128 + k] = __float2half(Wl[(long long)(row0 + k) * ldw + c]);
}

// h16[r][:] += vn[batch[r]][:]  (half2 lanes, grid = N*64/256 = 12500 exact)
__global__ void k_addvn16(__half* __restrict__ h16, const float* __restrict__ vn,
                          const int* __restrict__ batch) {
  int i2 = blockIdx.x * 256 + threadIdx.x;
  int r = i2 >> 6;
  int b = batch[r];
  __half2 hv = reinterpret_cast<__half2*>(h16)[i2];
  float2 vv = reinterpret_cast<const float2*>(vn)[(b << 6) + (i2 & 63)];
  reinterpret_cast<__half2*>(h16)[i2] =
      __floats2half2_rn(__low2float(hv) + vv.x, __high2float(hv) + vv.y);
}

// ---------------------------------------------------------------------------
// CSR build: histogram -> 2-level exclusive scan -> scatter (dst-sorted int2(src,eid))
__global__ void k_hist(const int* __restrict__ dst, int* __restrict__ cnt) {
  int e = blockIdx.x * 256 + threadIdx.x;   // grid covers E exactly
  atomicAdd(&cnt[dst[e]], 1);
}

__global__ void k_scan_block(const int* __restrict__ cnt, int* __restrict__ off,
                             int* __restrict__ bsum) {
  __shared__ int s[256];
  int idx = blockIdx.x * 256 + threadIdx.x;
  int v = (idx < N) ? cnt[idx] : 0;
  s[threadIdx.x] = v;
  __syncthreads();
  for (int o = 1; o < 256; o <<= 1) {
    int t = (threadIdx.x >= o) ? s[threadIdx.x - o] : 0;
    __syncthreads();
    s[threadIdx.x] += t;
    __syncthreads();
  }
  if (idx < N) off[idx + 1] = s[threadIdx.x];
  if (threadIdx.x == 255) bsum[blockIdx.x] = s[255];
  if (idx == 0) off[0] = 0;
}

__global__ void k_scan_bsum(int* __restrict__ bsum) {   // single block
  __shared__ int s[256];
  int v = (threadIdx.x < NB_SCAN) ? bsum[threadIdx.x] : 0;
  s[threadIdx.x] = v;
  __syncthreads();
  for (int o = 1; o < 256; o <<= 1) {
    int t = (threadIdx.x >= o) ? s[threadIdx.x - o] : 0;
    __syncthreads();
    s[threadIdx.x] += t;
    __syncthreads();
  }
  if (threadIdx.x < NB_SCAN) bsum[threadIdx.x] = s[threadIdx.x];  // inclusive
}

__global__ void k_scan_add(int* __restrict__ off, const int* __restrict__ bsum) {
  int idx = blockIdx.x * 256 + threadIdx.x;
  if (idx < N && blockIdx.x > 0) off[idx + 1] += bsum[blockIdx.x - 1];
}

__global__ void k_scatter(const int* __restrict__ src, const int* __restrict__ dst,
                          const int* __restrict__ off, int* __restrict__ cur,
                          int2* __restrict__ sE) {
  int e = blockIdx.x * 256 + threadIdx.x;   // grid covers E exactly
  int d = dst[e];
  int p = off[d] + atomicAdd(&cur[d], 1);
  sE[p] = make_int2(src[e], e);
}

// ---------------------------------------------------------------------------
// CSR aggregation, atomic-free. One 64-lane wave per dst node (2 adjacent cols/lane).
// hpa16[d] = h16[d] + sum_{e in in(d)} relu(h16[src[e]] + edge_attr[e] @ We + be)
__global__ __launch_bounds__(256) void k_agg(
    const float* __restrict__ edge_attr, const float* __restrict__ We,
    const float* __restrict__ be, const int* __restrict__ off,
    const int2* __restrict__ sE, const __half* __restrict__ h16,
    __half* __restrict__ hpa16) {
  __shared__ float sWe[16 * 128];
  __shared__ float sbe[128];
  int tid = threadIdx.x;
  for (int i = tid; i < 2048; i += 256) sWe[i] = We[i];
  if (tid < 128) sbe[tid] = be[tid];
  __syncthreads();
  int w = tid >> 6;       // wave id in block: 4 nodes per block
  int lane = tid & 63;
  int d = blockIdx.x * 4 + w;   // grid = 12500 -> covers N exactly
  int j0 = off[d], j1 = off[d + 1];
  const float2* sWe2 = reinterpret_cast<const float2*>(sWe);
  const __half2* h2 = reinterpret_cast<const __half2*>(h16);
  float2 bev = reinterpret_cast<const float2*>(sbe)[lane];
  float a0 = 0.f, a1 = 0.f;
  for (int j = j0; j < j1; ++j) {
    int2 se = sE[j];                                   // broadcast load
    const float4* ea4 = reinterpret_cast<const float4*>(edge_attr) + se.y * 4;
    float qa[16];
    *reinterpret_cast<float4*>(qa)      = ea4[0];
    *reinterpret_cast<float4*>(qa + 4)  = ea4[1];
    *reinterpret_cast<float4*>(qa + 8)  = ea4[2];
    *reinterpret_cast<float4*>(qa + 12) = ea4[3];
    float ev0 = bev.x, ev1 = bev.y;
#pragma unroll
    for (int k = 0; k < 16; ++k) {
      float2 wv = sWe2[k * 64 + lane];
      ev0 += qa[k] * wv.x;
      ev1 += qa[k] * wv.y;
    }
    __half2 hv = h2[se.x * 64 + lane];
    a0 += fmaxf(__low2float(hv) + ev0, 0.f);
    a1 += fmaxf(__high2float(hv) + ev1, 0.f);
  }
  __half2 hd = h2[d * 64 + lane];
  reinterpret_cast<__half2*>(hpa16)[d * 64 + lane] =
      __floats2half2_rn(__low2float(hd) + a0, __high2float(hd) + a1);
}

// ---------------------------------------------------------------------------
// fp16 MFMA GEMM, K=128 fixed. C[M x ldc] fp32 (or fp16 when OUT_F16).
// A [M][128] f16 row-major; Bt [ldc][128] f16 with Bt[c][k] = W[k][c].
// Block: 64 rows x 128 cols, 4 waves in 2x2, wave tile 32x64.
// mfma_f32_16x16x32_f16; A/B frags: row/col = lane&15, k = (lane>>4)*8 (+kk*32).
// C/D: col = lane&15, row = (lane>>4)*4 + reg  [m89-verified].
template<bool HAS_BIAS, bool HAS_ROWBIAS, bool OUT_F16>
__global__ __launch_bounds__(256) void k_mgemm(
    const __half* __restrict__ A, const __half* __restrict__ Bt,
    const float* __restrict__ bias,
    const float* __restrict__ rowbias, const int* __restrict__ batch,
    float* __restrict__ Cf, __half* __restrict__ Ch, int ldc, int M) {
  __shared__ _Float16 Ash[64][136];    // +8 pad: row stride 272 B = 17*16 B
  __shared__ _Float16 Bsh[128][136];
  int tid = threadIdx.x;
  int m0 = blockIdx.x * 64;
  int c0 = blockIdx.y * 128;
  // stage A: 64 rows x 16 chunks(8 f16) = 1024 chunks
#pragma unroll
  for (int it = 0; it < 4; ++it) {
    int idx = it * 256 + tid;
    int r = idx >> 4, ck = idx & 15;
    f16x8 v = {0, 0, 0, 0, 0, 0, 0, 0};
    if (m0 + r < M)
      v = *reinterpret_cast<const f16x8*>(A + (((long long)(m0 + r)) << 7) + ck * 8);
    *reinterpret_cast<f16x8*>(&Ash[r][ck * 8]) = v;
  }
  // stage B: 128 rows x 16 chunks = 2048 chunks
#pragma unroll
  for (int it = 0; it < 8; ++it) {
    int idx = it * 256 + tid;
    int r = idx >> 4, ck = idx & 15;
    f16x8 v = *reinterpret_cast<const f16x8*>(Bt + (((long long)(c0 + r)) << 7) + ck * 8);
    *reinterpret_cast<f16x8*>(&Bsh[r][ck * 8]) = v;
  }
  __syncthreads();

  int wid = tid >> 6, lane = tid & 63;
  int wr = wid >> 1, wc = wid & 1;        // 2x2 wave grid, wave tile 32x64
  int lrow = lane & 15;
  int lk = (lane >> 4) * 8;
  f32x4 acc[2][4];
#pragma unroll
  for (int fm = 0; fm < 2; ++fm)
#pragma unroll
    for (int fn = 0; fn < 4; ++fn) acc[fm][fn] = (f32x4){0.f, 0.f, 0.f, 0.f};

#pragma unroll
  for (int kk = 0; kk < 4; ++kk) {
    f16x8 af[2], bf[4];
#pragma unroll
    for (int fm = 0; fm < 2; ++fm)
      af[fm] = *reinterpret_cast<const f16x8*>(&Ash[wr * 32 + fm * 16 + lrow][kk * 32 + lk]);
#pragma unroll
    for (int fn = 0; fn < 4; ++fn)
      bf[fn] = *reinterpret_cast<const f16x8*>(&Bsh[wc * 64 + fn * 16 + lrow][kk * 32 + lk]);
#pragma unroll
    for (int fm = 0; fm < 2; ++fm)
#pragma unroll
      for (int fn = 0; fn < 4; ++fn)
        acc[fm][fn] = __builtin_amdgcn_mfma_f32_16x16x32_f16(af[fm], bf[fn], acc[fm][fn], 0, 0, 0);
  }

  // epilogue
#pragma unroll
  for (int fn = 0; fn < 4; ++fn) {
    int col = c0 + wc * 64 + fn * 16 + lrow;
    float bb = HAS_BIAS ? bias[col] : 0.f;
#pragma unroll
    for (int fm = 0; fm < 2; ++fm) {
      int grb = m0 + wr * 32 + fm * 16 + (lane >> 4) * 4;
#pragma unroll
      for (int j = 0; j < 4; ++j) {
        int gr = grb + j;
        if (gr < M) {
          float v = acc[fm][fn][j] + bb;
          if (HAS_ROWBIAS)
            v += rowbias[(long long)batch[gr] * ldc + col];
          if (OUT_F16)
            Ch[(long long)gr * ldc + col] = __float2half(v);
          else
            Cf[(long long)gr * ldc + col] = v;
        }
      }
    }
  }
}

// ---------------------------------------------------------------------------
// Generic fp32 vector GEMM for the small (G-row) matmuls.
template<int K, bool HAS_BIAS, bool HAS_ROWBIAS, bool RELU>
__global__ __launch_bounds__(256) void k_gemm(
    const float* __restrict__ A1,
    const float* __restrict__ W, int ldw,
    const float* __restrict__ bias,
    const float* __restrict__ rowbias, const int* __restrict__ batch,
    float* __restrict__ C, int M) {
  __shared__ float As[32 * K];
  constexpr int K4 = K / 4;
  int tid = threadIdx.x;
  int m0 = blockIdx.x * 32;
#pragma unroll
  for (int it = 0; it < K / 32; ++it) {
    int e4 = it * 256 + tid;
    int r = e4 / K4;
    int k4 = e4 % K4;
    int gr = m0 + r;
    float4 v = make_float4(0.f, 0.f, 0.f, 0.f);
    if (gr < M) v = reinterpret_cast<const float4*>(A1)[(long long)gr * K4 + k4];
    reinterpret_cast<float4*>(As)[e4] = v;
  }
  __syncthreads();

  int cg = tid & 31;
  int rg = tid >> 5;
  int col = blockIdx.y * 128 + cg * 4;
  float4 acc[4];
#pragma unroll
  for (int j = 0; j < 4; ++j) acc[j] = make_float4(0.f, 0.f, 0.f, 0.f);
  const float4* W4 = reinterpret_cast<const float4*>(W);
  const float4* As4 = reinterpret_cast<const float4*>(As);
#pragma unroll 8
  for (int k = 0; k < K; k += 4) {
    float4 w0 = W4[((k + 0) * ldw + col) >> 2];
    float4 w1 = W4[((k + 1) * ldw + col) >> 2];
    float4 w2 = W4[((k + 2) * ldw + col) >> 2];
    float4 w3 = W4[((k + 3) * ldw + col) >> 2];
#pragma unroll
    for (int j = 0; j < 4; ++j) {
      float4 a = As4[(rg + j * 8) * K4 + (k >> 2)];
      acc[j].x += a.x * w0.x + a.y * w1.x + a.z * w2.x + a.w * w3.x;
      acc[j].y += a.x * w0.y + a.y * w1.y + a.z * w2.y + a.w * w3.y;
      acc[j].z += a.x * w0.z + a.y * w1.z + a.z * w2.z + a.w * w3.z;
      acc[j].w += a.x * w0.w + a.y * w1.w + a.z * w2.w + a.w * w3.w;
    }
  }
  float4 bb = make_float4(0.f, 0.f, 0.f, 0.f);
  if (HAS_BIAS) bb = reinterpret_cast<const float4*>(bias)[blockIdx.y * 32 + cg];
#pragma unroll
  for (int j = 0; j < 4; ++j) {
    int gr = m0 + rg + j * 8;
    if (gr < M) {
      float4 v = acc[j];
      v.x += bb.x; v.y += bb.y; v.z += bb.z; v.w += bb.w;
      if (HAS_ROWBIAS) {
        int b = batch[gr];
        float4 rb = reinterpret_cast<const float4*>(rowbias)[((long long)b * ldw + col) >> 2];
        v.x += rb.x; v.y += rb.y; v.z += rb.z; v.w += rb.w;
      }
      if (RELU) {
        v.x = fmaxf(v.x, 0.f); v.y = fmaxf(v.y, 0.f);
        v.z = fmaxf(v.z, 0.f); v.w = fmaxf(v.w, 0.f);
      }
      reinterpret_cast<float4*>(C)[((long long)gr * ldw + col) >> 2] = v;
    }
  }
}

// ---------------------------------------------------------------------------
// Column sum / sumsq over M rows of X[M][NC] -> stats[0:NC]=sum, stats[NC:2NC]=sumsq
template<int NC>
__global__ void k_stats(const float* __restrict__ X, int M, float* __restrict__ stats) {
  constexpr int RP = 256 / NC;
  int c = threadIdx.x % NC;
  int rsub = threadIdx.x / NC;
  float s = 0.f, s2 = 0.f;
  for (int r = blockIdx.x * RP + rsub; r < M; r += gridDim.x * RP) {
    float v = X[(long long)r * NC + c];
    s += v; s2 += v * v;
  }
  if (RP > 1) {
    __shared__ float ls[512];
    ls[threadIdx.x] = s; ls[256 + threadIdx.x] = s2;
    __syncthreads();
    if (rsub == 0) {
#pragma unroll
      for (int j = 1; j < RP; ++j) { s += ls[j * NC + c]; s2 += ls[256 + j * NC + c]; }
    }
  }
  if (rsub == 0) { atomicAdd(&stats[c], s); atomicAdd(&stats[NC + c], s2); }
}

// h16 = (half) relu(bn(z)); half2 lanes, grid = N*64/256 = 12500 exact
__global__ void k_bn16(const float* __restrict__ X, const float* __restrict__ stats,
                       const float* __restrict__ gam, const float* __restrict__ beta,
                       __half* __restrict__ out16, float invM) {
  int i2 = blockIdx.x * 256 + threadIdx.x;
  int c = (i2 & 63) * 2;
  float2 xv = reinterpret_cast<const float2*>(X)[i2];
  float m0 = stats[c] * invM;
  float v0 = stats[128 + c] * invM - m0 * m0;
  float m1 = stats[c + 1] * invM;
  float v1 = stats[128 + c + 1] * invM - m1 * m1;
  float r0 = fmaxf((xv.x - m0) * rsqrtf(v0 + EPS) * gam[c] + beta[c], 0.f);
  float r1 = fmaxf((xv.y - m1) * rsqrtf(v1 + EPS) * gam[c + 1] + beta[c + 1], 0.f);
  reinterpret_cast<__half2*>(out16)[i2] = __floats2half2_rn(r0, r1);
}

// pooled[g] += relu(bn(z2[r])) for rows r with batch[r]==g (batch sorted).
__global__ void k_pool(const float* __restrict__ z2, const float* __restrict__ stats,
                       const float* __restrict__ gam, const float* __restrict__ beta,
                       const int* __restrict__ batch, float* __restrict__ pooled) {
  int c = threadIdx.x;  // 256 cols
  const float invM = 1.f / (float)N;
  float mean = stats[c] * invM;
  float var = stats[256 + c] * invM - mean * mean;
  float scale = rsqrtf(var + EPS) * gam[c];
  float shift = beta[c] - mean * scale;
  int r0 = blockIdx.x * 128;
  int r1 = min(r0 + 128, N);
  if (r0 >= N) return;
  int curg = batch[r0];
  float acc = 0.f;
  for (int r = r0; r < r1; ++r) {
    int gb = batch[r];
    float v = fmaxf(z2[(long long)r * 256 + c] * scale + shift, 0.f);
    if (gb != curg) { atomicAdd(&pooled[curg * 256 + c], acc); acc = v; curg = gb; }
    else acc += v;
  }
  atomicAdd(&pooled[curg * 256 + c], acc);
}

// vn = relu(bn(zvn)); also write into hg concat buffer at layer offset
__global__ void k_vnapply(const float* __restrict__ zvn, const float* __restrict__ stats,
                          const float* __restrict__ gam, const float* __restrict__ beta,
                          float* __restrict__ vn, float* __restrict__ hgbuf, int layer) {
  int idx = blockIdx.x * 256 + threadIdx.x;  // G*H = 65536
  int c = idx & 127;
  int g = idx >> 7;
  const float invM = 1.f / (float)G;
  float mean = stats[c] * invM;
  float var = stats[128 + c] * invM - mean * mean;
  float v = fmaxf((zvn[idx] - mean) * rsqrtf(var + EPS) * gam[c] + beta[c], 0.f);
  vn[idx] = v;
  hgbuf[g * 384 + layer * 128 + c] = v;
}

// out[g] = hg2[g] @ pred_W2 + b2   (one wave per graph)
__global__ void k_pred2(const float* __restrict__ hg2, const float* __restrict__ W2,
                        const float* __restrict__ b2, float* __restrict__ out) {
  int g = blockIdx.x;
  int lane = threadIdx.x;
  float s = 0.f;
  for (int k = lane; k < 384; k += 64) s += hg2[g * 384 + k] * W2[k];
  for (int off = 32; off; off >>= 1) s += __shfl_down(s, off);
  if (lane == 0) out[g] = s + b2[0];
}

// ---------------------------------------------------------------------------
extern "C" void kernel_launch(void* const* d_in, const int* in_sizes, int n_in,
                              void* d_out, int out_size, void* d_ws, size_t ws_size,
                              hipStream_t stream) {
  const float* x         = (const float*)d_in[0];
  const float* edge_attr = (const float*)d_in[1];
  const float* atom_W    = (const float*)d_in[2];
  const float* atom_b    = (const float*)d_in[3];
  const float* vn_emb    = (const float*)d_in[4];
  const float* conv_We   = (const float*)d_in[5];
  const float* conv_be   = (const float*)d_in[6];
  const float* conv_W    = (const float*)d_in[7];
  const float* conv_b    = (const float*)d_in[8];
  const float* conv_g    = (const float*)d_in[9];
  const float* conv_beta = (const float*)d_in[10];
  const float* vn1_W     = (const float*)d_in[11];
  const float* vn1_b     = (const float*)d_in[12];
  const float* vn1_g     = (const float*)d_in[13];
  const float* vn1_beta  = (const float*)d_in[14];
  const float* vn2_W     = (const float*)d_in[15];
  const float* vn2_b     = (const float*)d_in[16];
  const float* vn2_g     = (const float*)d_in[17];
  const float* vn2_beta  = (const float*)d_in[18];
  const float* pred_W1   = (const float*)d_in[19];
  const float* pred_b1   = (const float*)d_in[20];
  const float* pred_W2   = (const float*)d_in[21];
  const float* pred_b2   = (const float*)d_in[22];
  const int*   eidx      = (const int*)d_in[23];
  const int*   batch     = (const int*)d_in[24];
  const int* src = eidx;
  const int* dst = eidx + E;

  // Workspace layout (units: 4-byte float slots). Total ~18.1M slots = ~73 MB.
  float* ws    = (float*)d_ws;
  __half* h16  = (__half*)ws;                // N*128 halves = NH/2 slots
  float* bufB  = ws + NH / 2;                // 2*NH slots
  __half* hpa16= (__half*)bufB;              // N*128 halves (dead before z2 write)
  float* z     = bufB + NH;                  // N*128 f32
  float* z2    = bufB;                       // N*256 f32 (after hpa16/z dead)
  __half* x16  = (__half*)z;                 // N*128 halves (dead before conv gemm)
  float* U     = bufB + 2 * NH;              // G*256
  float* pooled= U + G * 256;                // G*256
  float* zvn   = pooled + G * 256;           // G*128
  float* vn    = zvn + G * 128;              // G*128
  float* hgbuf = vn + G * 128;               // G*384
  float* hg2   = hgbuf + G * 384;            // G*384
  float* stats = hg2 + G * 384;              // 512
  __half* atomWt = (__half*)(stats + 512);   // 128*128 halves
  __half* convWt = atomWt + 16384;           // 3 * 128*128
  __half* z2Wt   = convWt + 3 * 16384;       // 3 * 256*128
  int*  off    = (int*)(z2Wt + 3 * 32768);   // N+1 (padded 50002)
  int2* sE     = (int2*)(off + 50002);       // E int2
  // CSR build temporaries (dead before first k_agg) alias bufB:
  int* cnt  = (int*)bufB;
  int* cur  = cnt + N;
  int* bsum = cur + N;

  dim3 b256(256);

  // ---- CSR build (once; edge_index identical across layers) ----
  hipMemsetAsync(cnt, 0, (size_t)N * 4, stream);
  hipMemsetAsync(cur, 0, (size_t)N * 4, stream);
  k_hist<<<E / 256, b256, 0, stream>>>(dst, cnt);
  k_scan_block<<<NB_SCAN, b256, 0, stream>>>(cnt, off, bsum);
  k_scan_bsum<<<1, b256, 0, stream>>>(bsum);
  k_scan_add<<<NB_SCAN, b256, 0, stream>>>(off, bsum);
  k_scatter<<<E / 256, b256, 0, stream>>>(src, dst, off, cur, sE);

  k_init_vn<<<G * 128 / 256, b256, 0, stream>>>(vn_emb, vn);

  // ---- weight/input fp16 prep ----
  k_tof16<<<(N * 128 / 4 + 255) / 256, b256, 0, stream>>>(x, x16, N * 128 / 4);
  k_wt<<<dim3(64, 1), b256, 0, stream>>>(atom_W, atomWt, 128, 0, 128, 0, 0);
  k_wt<<<dim3(64, 3), b256, 0, stream>>>(conv_W, convWt, 128, 0, 128, 16384, 16384);
  k_wt<<<dim3(128, 3), b256, 0, stream>>>(vn1_W, z2Wt, 256, 128, 256, 65536, 32768);

  // h16 = x16 @ atom_W + atom_b   (fp16 out)
  k_mgemm<true, false, true><<<dim3(782, 1), b256, 0, stream>>>(
      x16, atomWt, atom_b, nullptr, nullptr, nullptr, h16, 128, N);

  for (int i = 0; i < 3; ++i) {
    k_addvn16<<<12500, b256, 0, stream>>>(h16, vn, batch);
    // hpa16 = h16 + sum_in relu(h16[src] + ea@We + be)   (atomic-free CSR gather)
    k_agg<<<12500, b256, 0, stream>>>(edge_attr, conv_We + i * 2048, conv_be + i * 128,
                                      off, sE, h16, hpa16);
    // z = hpa16 @ conv_W[i] + conv_b[i]   (MFMA)
    k_mgemm<true, false, false><<<dim3(782, 1), b256, 0, stream>>>(
        hpa16, convWt + i * 16384, conv_b + i * 128, nullptr, nullptr, z, nullptr, 128, N);
    hipMemsetAsync(stats, 0, 2048, stream);
    k_stats<128><<<256, b256, 0, stream>>>(z, N, stats);
    // h16 = relu(bn(z))
    k_bn16<<<12500, b256, 0, stream>>>(z, stats, conv_g + i * 128, conv_beta + i * 128,
                                       h16, 1.f / (float)N);
    // U = vn @ vn1_W[i][:128,:] + vn1_b[i]   (512 distinct rows of vn[batch])
    k_gemm<128, true, false, false><<<dim3(16, 2), b256, 0, stream>>>(
        vn, vn1_W + i * 256 * 256, 256, vn1_b + i * 256, nullptr, nullptr, U, G);
    // z2 = h16 @ vn1_W[i][128:,:] + U[batch]   (MFMA, rowbias gather)
    k_mgemm<false, true, false><<<dim3(782, 2), b256, 0, stream>>>(
        h16, z2Wt + i * 32768, nullptr, U, batch, z2, nullptr, 256, N);
    hipMemsetAsync(stats, 0, 2048, stream);
    k_stats<256><<<256, b256, 0, stream>>>(z2, N, stats);
    hipMemsetAsync(pooled, 0, (size_t)G * 256 * 4, stream);
    k_pool<<<(N + 127) / 128, b256, 0, stream>>>(
        z2, stats, vn1_g + i * 256, vn1_beta + i * 256, batch, pooled);
    // zvn = pooled @ vn2_W[i] + vn2_b[i]
    k_gemm<256, true, false, false><<<dim3(16, 1), b256, 0, stream>>>(
        pooled, vn2_W + i * 256 * 128, 128, vn2_b + i * 128, nullptr, nullptr, zvn, G);
    hipMemsetAsync(stats, 0, 2048, stream);
    k_stats<128><<<16, b256, 0, stream>>>(zvn, G, stats);
    k_vnapply<<<G * 128 / 256, b256, 0, stream>>>(
        zvn, stats, vn2_g + i * 128, vn2_beta + i * 128, vn, hgbuf, i);
  }
  // hg2 = relu(hgbuf @ pred_W1 + pred_b1)
  k_gemm<384, true, false, true><<<dim3(16, 3), b256, 0, stream>>>(
      hgbuf, pred_W1, 384, pred_b1, nullptr, nullptr, hg2, G);
  k_pred2<<<G, 64, 0, stream>>>(hg2, pred_W2, pred_b2, (float*)d_out);
}

// Round 5
// 1328.625 us; speedup vs baseline: 1.7663x; 1.3114x over previous
//
#include <hip/hip_runtime.h>
#include <hip/hip_fp16.h>

// Problem constants (fixed by the reference)
constexpr int N = 50000;
constexpr int E = 800000;
constexpr int G = 512;
constexpr int H = 128;
constexpr long long NH = (long long)N * H;   // 6,400,000 elements
constexpr float EPS = 1e-5f;
constexpr int NB_SCAN = 196;                 // ceil(50000/256)

typedef _Float16 f16x8 __attribute__((ext_vector_type(8)));
typedef _Float16 f16x2 __attribute__((ext_vector_type(2)));
typedef float f32x4 __attribute__((ext_vector_type(4)));

// ---------------------------------------------------------------------------
// vn[g][c] = vn_emb[c]
__global__ void k_init_vn(const float* __restrict__ vn_emb, float* __restrict__ vn) {
  int idx = blockIdx.x * 256 + threadIdx.x;   // G*H = 65536 exactly
  vn[idx] = vn_emb[idx & 127];
}

// fp32 -> fp16 bulk convert (float4 -> half2 x2), grid covers n4 exactly
__global__ void k_tof16(const float* __restrict__ in, __half* __restrict__ out, int n4) {
  int i = blockIdx.x * 256 + threadIdx.x;
  if (i >= n4) return;
  float4 v = reinterpret_cast<const float4*>(in)[i];
  __half2* o = reinterpret_cast<__half2*>(out);
  o[i * 2]     = __floats2half2_rn(v.x, v.y);
  o[i * 2 + 1] = __floats2half2_rn(v.z, v.w);
}

// Wt[c][k] = (half) W[(row0+k)*ldw + c], K=128 fixed; one layer per blockIdx.y
__global__ void k_wt(const float* __restrict__ W, __half* __restrict__ Wt,
                     int ldw, int row0, int cols, long long wstride, int wtstride) {
  const float* Wl = W + (long long)blockIdx.y * wstride;
  __half* Wtl = Wt + (long long)blockIdx.y * wtstride;
  int idx = blockIdx.x * 256 + threadIdx.x;   // cols*128, exact multiple of 256
  int k = idx & 127, c = idx >> 7;
  Wtl[c * 128 + k] = __float2half(Wl[(long long)(row0 + k) * ldw + c]);
}

// h16[r][:] += vn[batch[r]][:]  (half2 lanes, grid = N*64/256 = 12500 exact)
__global__ void k_addvn16(__half* __restrict__ h16, const float* __restrict__ vn,
                          const int* __restrict__ batch) {
  int i2 = blockIdx.x * 256 + threadIdx.x;
  int r = i2 >> 6;
  int b = batch[r];
  __half2 hv = reinterpret_cast<__half2*>(h16)[i2];
  float2 vv = reinterpret_cast<const float2*>(vn)[(b << 6) + (i2 & 63)];
  reinterpret_cast<__half2*>(h16)[i2] =
      __floats2half2_rn(__low2float(hv) + vv.x, __high2float(hv) + vv.y);
}

// ---------------------------------------------------------------------------
// CSR build: histogram -> 2-level exclusive scan -> scatter.
// Scatter also permutes edge_attr into dst-order fp16 (eap) so per-layer
// k_agg reads are sequential.
__global__ void k_hist(const int* __restrict__ dst, int* __restrict__ cnt) {
  int e = blockIdx.x * 256 + threadIdx.x;   // grid covers E exactly
  atomicAdd(&cnt[dst[e]], 1);
}

__global__ void k_scan_block(const int* __restrict__ cnt, int* __restrict__ off,
                             int* __restrict__ bsum) {
  __shared__ int s[256];
  int idx = blockIdx.x * 256 + threadIdx.x;
  int v = (idx < N) ? cnt[idx] : 0;
  s[threadIdx.x] = v;
  __syncthreads();
  for (int o = 1; o < 256; o <<= 1) {
    int t = (threadIdx.x >= o) ? s[threadIdx.x - o] : 0;
    __syncthreads();
    s[threadIdx.x] += t;
    __syncthreads();
  }
  if (idx < N) off[idx + 1] = s[threadIdx.x];
  if (threadIdx.x == 255) bsum[blockIdx.x] = s[255];
  if (idx == 0) off[0] = 0;
}

__global__ void k_scan_bsum(int* __restrict__ bsum) {   // single block
  __shared__ int s[256];
  int v = (threadIdx.x < NB_SCAN) ? bsum[threadIdx.x] : 0;
  s[threadIdx.x] = v;
  __syncthreads();
  for (int o = 1; o < 256; o <<= 1) {
    int t = (threadIdx.x >= o) ? s[threadIdx.x - o] : 0;
    __syncthreads();
    s[threadIdx.x] += t;
    __syncthreads();
  }
  if (threadIdx.x < NB_SCAN) bsum[threadIdx.x] = s[threadIdx.x];  // inclusive
}

__global__ void k_scan_add(int* __restrict__ off, const int* __restrict__ bsum) {
  int idx = blockIdx.x * 256 + threadIdx.x;
  if (idx < N && blockIdx.x > 0) off[idx + 1] += bsum[blockIdx.x - 1];
}

__global__ void k_scatter(const int* __restrict__ src, const int* __restrict__ dst,
                          const int* __restrict__ off, int* __restrict__ cur,
                          int* __restrict__ srcp, __half* __restrict__ eap,
                          const float* __restrict__ edge_attr) {
  int e = blockIdx.x * 256 + threadIdx.x;   // grid covers E exactly
  int d = dst[e];
  int p = off[d] + atomicAdd(&cur[d], 1);
  srcp[p] = src[e];
  const float4* ea4 = reinterpret_cast<const float4*>(edge_attr) + e * 4;
  float4 a0 = ea4[0], a1 = ea4[1], a2 = ea4[2], a3 = ea4[3];
  __half2* o = reinterpret_cast<__half2*>(eap + (long long)p * 16);
  o[0] = __floats2half2_rn(a0.x, a0.y);
  o[1] = __floats2half2_rn(a0.z, a0.w);
  o[2] = __floats2half2_rn(a1.x, a1.y);
  o[3] = __floats2half2_rn(a1.z, a1.w);
  o[4] = __floats2half2_rn(a2.x, a2.y);
  o[5] = __floats2half2_rn(a2.z, a2.w);
  o[6] = __floats2half2_rn(a3.x, a3.y);
  o[7] = __floats2half2_rn(a3.z, a3.w);
}

// ---------------------------------------------------------------------------
// CSR aggregation, atomic-free, LDS-free. One 64-lane wave per dst node
// (2 adjacent cols/lane). We panel held in registers as packed half2;
// ev computed via v_dot2_f32_f16 (f32 accumulate). Edge loop unrolled x2.
// hpa16[d] = h16[d] + sum_{e in in(d)} relu(h16[src[e]] + ea[e] @ We + be)
__global__ __launch_bounds__(256) void k_agg(
    const __half* __restrict__ eap, const float* __restrict__ We,
    const float* __restrict__ be, const int* __restrict__ off,
    const int* __restrict__ srcp, const __half* __restrict__ h16,
    __half* __restrict__ hpa16) {
  int tid = threadIdx.x;
  int lane = tid & 63;
  int c0 = lane * 2;
  // Pack this lane's 2 We columns over k-pairs: wc0[kk] = (We[2kk][c0], We[2kk+1][c0])
  f16x2 wc0[8], wc1[8];
#pragma unroll
  for (int kk = 0; kk < 8; ++kk) {
    f16x2 w0, w1;
    w0[0] = (_Float16)We[(2 * kk) * 128 + c0];
    w0[1] = (_Float16)We[(2 * kk + 1) * 128 + c0];
    w1[0] = (_Float16)We[(2 * kk) * 128 + c0 + 1];
    w1[1] = (_Float16)We[(2 * kk + 1) * 128 + c0 + 1];
    wc0[kk] = w0; wc1[kk] = w1;
  }
  float2 bev = reinterpret_cast<const float2*>(be)[lane];
  int d = blockIdx.x * 4 + (tid >> 6);   // grid = 12500 -> covers N exactly
  int j0 = off[d], j1 = off[d + 1];
  const __half2* h2 = reinterpret_cast<const __half2*>(h16);
  const f16x2* e2 = reinterpret_cast<const f16x2*>(eap);
  float a0 = 0.f, a1 = 0.f, b0 = 0.f, b1 = 0.f;
  int j = j0;
  for (; j + 1 < j1; j += 2) {
    int sA = srcp[j], sB = srcp[j + 1];
    __half2 hA = h2[(long long)sA * 64 + lane];
    __half2 hB = h2[(long long)sB * 64 + lane];
    float evA0 = bev.x, evA1 = bev.y, evB0 = bev.x, evB1 = bev.y;
#pragma unroll
    for (int kk = 0; kk < 8; ++kk) {
      f16x2 ea = e2[(long long)j * 8 + kk];
      f16x2 eb = e2[(long long)(j + 1) * 8 + kk];
      evA0 = __builtin_amdgcn_fdot2(ea, wc0[kk], evA0, false);
      evA1 = __builtin_amdgcn_fdot2(ea, wc1[kk], evA1, false);
      evB0 = __builtin_amdgcn_fdot2(eb, wc0[kk], evB0, false);
      evB1 = __builtin_amdgcn_fdot2(eb, wc1[kk], evB1, false);
    }
    a0 += fmaxf(__low2float(hA) + evA0, 0.f);
    a1 += fmaxf(__high2float(hA) + evA1, 0.f);
    b0 += fmaxf(__low2float(hB) + evB0, 0.f);
    b1 += fmaxf(__high2float(hB) + evB1, 0.f);
  }
  if (j < j1) {
    int sA = srcp[j];
    __half2 hA = h2[(long long)sA * 64 + lane];
    float evA0 = bev.x, evA1 = bev.y;
#pragma unroll
    for (int kk = 0; kk < 8; ++kk) {
      f16x2 ea = e2[(long long)j * 8 + kk];
      evA0 = __builtin_amdgcn_fdot2(ea, wc0[kk], evA0, false);
      evA1 = __builtin_amdgcn_fdot2(ea, wc1[kk], evA1, false);
    }
    a0 += fmaxf(__low2float(hA) + evA0, 0.f);
    a1 += fmaxf(__high2float(hA) + evA1, 0.f);
  }
  a0 += b0; a1 += b1;
  __half2 hd = h2[(long long)d * 64 + lane];
  reinterpret_cast<__half2*>(hpa16)[(long long)d * 64 + lane] =
      __floats2half2_rn(__low2float(hd) + a0, __high2float(hd) + a1);
}

// ---------------------------------------------------------------------------
// fp16 MFMA GEMM, K=128 fixed. C[M x ldc] fp32 (or fp16 when OUT_F16).
// A [M][128] f16 row-major; Bt [ldc][128] f16 with Bt[c][k] = W[k][c].
// Block: 64 rows x 128 cols, 4 waves in 2x2, wave tile 32x64.
// STATS: fused column sum/sumsq -> atomicAdd into stats[0:ldc], stats[ldc:2ldc]
// (stats must be pre-zeroed; only rows < M contribute).
template<bool HAS_BIAS, bool HAS_ROWBIAS, bool OUT_F16, bool STATS>
__global__ __launch_bounds__(256) void k_mgemm(
    const __half* __restrict__ A, const __half* __restrict__ Bt,
    const float* __restrict__ bias,
    const float* __restrict__ rowbias, const int* __restrict__ batch,
    float* __restrict__ Cf, __half* __restrict__ Ch,
    float* __restrict__ stats, int ldc, int M) {
  __shared__ _Float16 Ash[64][136];    // +8 pad: row stride 272 B = 17*16 B
  __shared__ _Float16 Bsh[128][136];
  int tid = threadIdx.x;
  int m0 = blockIdx.x * 64;
  int c0 = blockIdx.y * 128;
  // stage A: 64 rows x 16 chunks(8 f16) = 1024 chunks
#pragma unroll
  for (int it = 0; it < 4; ++it) {
    int idx = it * 256 + tid;
    int r = idx >> 4, ck = idx & 15;
    f16x8 v = {0, 0, 0, 0, 0, 0, 0, 0};
    if (m0 + r < M)
      v = *reinterpret_cast<const f16x8*>(A + (((long long)(m0 + r)) << 7) + ck * 8);
    *reinterpret_cast<f16x8*>(&Ash[r][ck * 8]) = v;
  }
  // stage B: 128 rows x 16 chunks = 2048 chunks
#pragma unroll
  for (int it = 0; it < 8; ++it) {
    int idx = it * 256 + tid;
    int r = idx >> 4, ck = idx & 15;
    f16x8 v = *reinterpret_cast<const f16x8*>(Bt + (((long long)(c0 + r)) << 7) + ck * 8);
    *reinterpret_cast<f16x8*>(&Bsh[r][ck * 8]) = v;
  }
  __syncthreads();

  int wid = tid >> 6, lane = tid & 63;
  int wr = wid >> 1, wc = wid & 1;        // 2x2 wave grid, wave tile 32x64
  int lrow = lane & 15;
  int lk = (lane >> 4) * 8;
  f32x4 acc[2][4];
#pragma unroll
  for (int fm = 0; fm < 2; ++fm)
#pragma unroll
    for (int fn = 0; fn < 4; ++fn) acc[fm][fn] = (f32x4){0.f, 0.f, 0.f, 0.f};

#pragma unroll
  for (int kk = 0; kk < 4; ++kk) {
    f16x8 af[2], bf[4];
#pragma unroll
    for (int fm = 0; fm < 2; ++fm)
      af[fm] = *reinterpret_cast<const f16x8*>(&Ash[wr * 32 + fm * 16 + lrow][kk * 32 + lk]);
#pragma unroll
    for (int fn = 0; fn < 4; ++fn)
      bf[fn] = *reinterpret_cast<const f16x8*>(&Bsh[wc * 64 + fn * 16 + lrow][kk * 32 + lk]);
#pragma unroll
    for (int fm = 0; fm < 2; ++fm)
#pragma unroll
      for (int fn = 0; fn < 4; ++fn)
        acc[fm][fn] = __builtin_amdgcn_mfma_f32_16x16x32_f16(af[fm], bf[fn], acc[fm][fn], 0, 0, 0);
  }

  // epilogue (+ optional fused column stats)
  float ss[4], ss2[4];
#pragma unroll
  for (int fn = 0; fn < 4; ++fn) { ss[fn] = 0.f; ss2[fn] = 0.f; }
#pragma unroll
  for (int fn = 0; fn < 4; ++fn) {
    int col = c0 + wc * 64 + fn * 16 + lrow;
    float bb = HAS_BIAS ? bias[col] : 0.f;
#pragma unroll
    for (int fm = 0; fm < 2; ++fm) {
      int grb = m0 + wr * 32 + fm * 16 + (lane >> 4) * 4;
#pragma unroll
      for (int j = 0; j < 4; ++j) {
        int gr = grb + j;
        if (gr < M) {
          float v = acc[fm][fn][j] + bb;
          if (HAS_ROWBIAS)
            v += rowbias[(long long)batch[gr] * ldc + col];
          if (STATS) { ss[fn] += v; ss2[fn] += v * v; }
          if (OUT_F16)
            Ch[(long long)gr * ldc + col] = __float2half(v);
          else
            Cf[(long long)gr * ldc + col] = v;
        }
      }
    }
  }
  if (STATS) {
    __shared__ float sred[2][4][4][16];   // [s|s2][wid][fn][lrow]
#pragma unroll
    for (int fn = 0; fn < 4; ++fn) {
      float s = ss[fn], s2 = ss2[fn];
      s += __shfl_xor(s, 16);  s += __shfl_xor(s, 32);
      s2 += __shfl_xor(s2, 16); s2 += __shfl_xor(s2, 32);
      if (lane < 16) { sred[0][wid][fn][lane] = s; sred[1][wid][fn][lane] = s2; }
    }
    __syncthreads();
    if (wr == 0 && lane < 16) {           // waves 0,1 combine with waves 2,3
#pragma unroll
      for (int fn = 0; fn < 4; ++fn) {
        int col = c0 + wc * 64 + fn * 16 + lane;
        atomicAdd(&stats[col],       sred[0][wid][fn][lane] + sred[0][wid + 2][fn][lane]);
        atomicAdd(&stats[ldc + col], sred[1][wid][fn][lane] + sred[1][wid + 2][fn][lane]);
      }
    }
  }
}

// ---------------------------------------------------------------------------
// Generic fp32 vector GEMM for the small (G-row) matmuls.
template<int K, bool HAS_BIAS, bool HAS_ROWBIAS, bool RELU>
__global__ __launch_bounds__(256) void k_gemm(
    const float* __restrict__ A1,
    const float* __restrict__ W, int ldw,
    const float* __restrict__ bias,
    const float* __restrict__ rowbias, const int* __restrict__ batch,
    float* __restrict__ C, int M) {
  __shared__ float As[32 * K];
  constexpr int K4 = K / 4;
  int tid = threadIdx.x;
  int m0 = blockIdx.x * 32;
#pragma unroll
  for (int it = 0; it < K / 32; ++it) {
    int e4 = it * 256 + tid;
    int r = e4 / K4;
    int k4 = e4 % K4;
    int gr = m0 + r;
    float4 v = make_float4(0.f, 0.f, 0.f, 0.f);
    if (gr < M) v = reinterpret_cast<const float4*>(A1)[(long long)gr * K4 + k4];
    reinterpret_cast<float4*>(As)[e4] = v;
  }
  __syncthreads();

  int cg = tid & 31;
  int rg = tid >> 5;
  int col = blockIdx.y * 128 + cg * 4;
  float4 acc[4];
#pragma unroll
  for (int j = 0; j < 4; ++j) acc[j] = make_float4(0.f, 0.f, 0.f, 0.f);
  const float4* W4 = reinterpret_cast<const float4*>(W);
  const float4* As4 = reinterpret_cast<const float4*>(As);
#pragma unroll 8
  for (int k = 0; k < K; k += 4) {
    float4 w0 = W4[((k + 0) * ldw + col) >> 2];
    float4 w1 = W4[((k + 1) * ldw + col) >> 2];
    float4 w2 = W4[((k + 2) * ldw + col) >> 2];
    float4 w3 = W4[((k + 3) * ldw + col) >> 2];
#pragma unroll
    for (int j = 0; j < 4; ++j) {
      float4 a = As4[(rg + j * 8) * K4 + (k >> 2)];
      acc[j].x += a.x * w0.x + a.y * w1.x + a.z * w2.x + a.w * w3.x;
      acc[j].y += a.x * w0.y + a.y * w1.y + a.z * w2.y + a.w * w3.y;
      acc[j].z += a.x * w0.z + a.y * w1.z + a.z * w2.z + a.w * w3.z;
      acc[j].w += a.x * w0.w + a.y * w1.w + a.z * w2.w + a.w * w3.w;
    }
  }
  float4 bb = make_float4(0.f, 0.f, 0.f, 0.f);
  if (HAS_BIAS) bb = reinterpret_cast<const float4*>(bias)[blockIdx.y * 32 + cg];
#pragma unroll
  for (int j = 0; j < 4; ++j) {
    int gr = m0 + rg + j * 8;
    if (gr < M) {
      float4 v = acc[j];
      v.x += bb.x; v.y += bb.y; v.z += bb.z; v.w += bb.w;
      if (HAS_ROWBIAS) {
        int b = batch[gr];
        float4 rb = reinterpret_cast<const float4*>(rowbias)[((long long)b * ldw + col) >> 2];
        v.x += rb.x; v.y += rb.y; v.z += rb.z; v.w += rb.w;
      }
      if (RELU) {
        v.x = fmaxf(v.x, 0.f); v.y = fmaxf(v.y, 0.f);
        v.z = fmaxf(v.z, 0.f); v.w = fmaxf(v.w, 0.f);
      }
      reinterpret_cast<float4*>(C)[((long long)gr * ldw + col) >> 2] = v;
    }
  }
}

// ---------------------------------------------------------------------------
// Column sum / sumsq over M rows of X[M][NC] -> stats[0:NC]=sum, stats[NC:2NC]=sumsq
template<int NC>
__global__ void k_stats(const float* __restrict__ X, int M, float* __restrict__ stats) {
  constexpr int RP = 256 / NC;
  int c = threadIdx.x % NC;
  int rsub = threadIdx.x / NC;
  float s = 0.f, s2 = 0.f;
  for (int r = blockIdx.x * RP + rsub; r < M; r += gridDim.x * RP) {
    float v = X[(long long)r * NC + c];
    s += v; s2 += v * v;
  }
  if (RP > 1) {
    __shared__ float ls[512];
    ls[threadIdx.x] = s; ls[256 + threadIdx.x] = s2;
    __syncthreads();
    if (rsub == 0) {
#pragma unroll
      for (int j = 1; j < RP; ++j) { s += ls[j * NC + c]; s2 += ls[256 + j * NC + c]; }
    }
  }
  if (rsub == 0) { atomicAdd(&stats[c], s); atomicAdd(&stats[NC + c], s2); }
}

// h16 = (half) relu(bn(z)); half2 lanes, grid = N*64/256 = 12500 exact
__global__ void k_bn16(const float* __restrict__ X, const float* __restrict__ stats,
                       const float* __restrict__ gam, const float* __restrict__ beta,
                       __half* __restrict__ out16, float invM) {
  int i2 = blockIdx.x * 256 + threadIdx.x;
  int c = (i2 & 63) * 2;
  float2 xv = reinterpret_cast<const float2*>(X)[i2];
  float m0 = stats[c] * invM;
  float v0 = stats[128 + c] * invM - m0 * m0;
  float m1 = stats[c + 1] * invM;
  float v1 = stats[128 + c + 1] * invM - m1 * m1;
  float r0 = fmaxf((xv.x - m0) * rsqrtf(v0 + EPS) * gam[c] + beta[c], 0.f);
  float r1 = fmaxf((xv.y - m1) * rsqrtf(v1 + EPS) * gam[c + 1] + beta[c + 1], 0.f);
  reinterpret_cast<__half2*>(out16)[i2] = __floats2half2_rn(r0, r1);
}

// pooled[g] += relu(bn(z2[r])) for rows r with batch[r]==g (batch sorted).
__global__ void k_pool(const float* __restrict__ z2, const float* __restrict__ stats,
                       const float* __restrict__ gam, const float* __restrict__ beta,
                       const int* __restrict__ batch, float* __restrict__ pooled) {
  int c = threadIdx.x;  // 256 cols
  const float invM = 1.f / (float)N;
  float mean = stats[c] * invM;
  float var = stats[256 + c] * invM - mean * mean;
  float scale = rsqrtf(var + EPS) * gam[c];
  float shift = beta[c] - mean * scale;
  int r0 = blockIdx.x * 128;
  int r1 = min(r0 + 128, N);
  if (r0 >= N) return;
  int curg = batch[r0];
  float acc = 0.f;
  for (int r = r0; r < r1; ++r) {
    int gb = batch[r];
    float v = fmaxf(z2[(long long)r * 256 + c] * scale + shift, 0.f);
    if (gb != curg) { atomicAdd(&pooled[curg * 256 + c], acc); acc = v; curg = gb; }
    else acc += v;
  }
  atomicAdd(&pooled[curg * 256 + c], acc);
}

// vn = relu(bn(zvn)); also write into hg concat buffer at layer offset
__global__ void k_vnapply(const float* __restrict__ zvn, const float* __restrict__ stats,
                          const float* __restrict__ gam, const float* __restrict__ beta,
                          float* __restrict__ vn, float* __restrict__ hgbuf, int layer) {
  int idx = blockIdx.x * 256 + threadIdx.x;  // G*H = 65536
  int c = idx & 127;
  int g = idx >> 7;
  const float invM = 1.f / (float)G;
  float mean = stats[c] * invM;
  float var = stats[128 + c] * invM - mean * mean;
  float v = fmaxf((zvn[idx] - mean) * rsqrtf(var + EPS) * gam[c] + beta[c], 0.f);
  vn[idx] = v;
  hgbuf[g * 384 + layer * 128 + c] = v;
}

// out[g] = hg2[g] @ pred_W2 + b2   (one wave per graph)
__global__ void k_pred2(const float* __restrict__ hg2, const float* __restrict__ W2,
                        const float* __restrict__ b2, float* __restrict__ out) {
  int g = blockIdx.x;
  int lane = threadIdx.x;
  float s = 0.f;
  for (int k = lane; k < 384; k += 64) s += hg2[g * 384 + k] * W2[k];
  for (int off = 32; off; off >>= 1) s += __shfl_down(s, off);
  if (lane == 0) out[g] = s + b2[0];
}

// ---------------------------------------------------------------------------
extern "C" void kernel_launch(void* const* d_in, const int* in_sizes, int n_in,
                              void* d_out, int out_size, void* d_ws, size_t ws_size,
                              hipStream_t stream) {
  const float* x         = (const float*)d_in[0];
  const float* edge_attr = (const float*)d_in[1];
  const float* atom_W    = (const float*)d_in[2];
  const float* atom_b    = (const float*)d_in[3];
  const float* vn_emb    = (const float*)d_in[4];
  const float* conv_We   = (const float*)d_in[5];
  const float* conv_be   = (const float*)d_in[6];
  const float* conv_W    = (const float*)d_in[7];
  const float* conv_b    = (const float*)d_in[8];
  const float* conv_g    = (const float*)d_in[9];
  const float* conv_beta = (const float*)d_in[10];
  const float* vn1_W     = (const float*)d_in[11];
  const float* vn1_b     = (const float*)d_in[12];
  const float* vn1_g     = (const float*)d_in[13];
  const float* vn1_beta  = (const float*)d_in[14];
  const float* vn2_W     = (const float*)d_in[15];
  const float* vn2_b     = (const float*)d_in[16];
  const float* vn2_g     = (const float*)d_in[17];
  const float* vn2_beta  = (const float*)d_in[18];
  const float* pred_W1   = (const float*)d_in[19];
  const float* pred_b1   = (const float*)d_in[20];
  const float* pred_W2   = (const float*)d_in[21];
  const float* pred_b2   = (const float*)d_in[22];
  const int*   eidx      = (const int*)d_in[23];
  const int*   batch     = (const int*)d_in[24];
  const int* src = eidx;
  const int* dst = eidx + E;

  // Workspace layout (units: 4-byte slots). Total ~24.1M slots = ~96.5 MB.
  float* ws    = (float*)d_ws;
  __half* h16  = (__half*)ws;                // N*128 halves
  float* bufB  = ws + NH / 2;                // 2*NH slots
  __half* hpa16= (__half*)bufB;              // N*128 halves (dead before z2 write)
  float* z     = bufB + NH;                  // N*128 f32
  float* z2    = bufB;                       // N*256 f32 (after hpa16/z dead)
  __half* x16  = (__half*)z;                 // N*128 halves (dead before conv gemm)
  float* U     = bufB + 2 * NH;              // G*256
  float* pooled= U + G * 256;                // G*256
  float* zvn   = pooled + G * 256;           // G*128
  float* vn    = zvn + G * 128;              // G*128
  float* hgbuf = vn + G * 128;               // G*384
  float* hg2   = hgbuf + G * 384;            // G*384
  float* stats = hg2 + G * 384;              // 512
  __half* atomWt = (__half*)(stats + 512);   // 128*128 halves
  __half* convWt = atomWt + 16384;           // 3 * 128*128
  __half* z2Wt   = convWt + 3 * 16384;       // 3 * 256*128
  int*  off    = (int*)(z2Wt + 3 * 32768);   // N+1 (padded 50002)
  int*  srcp   = off + 50002;                // E ints (dst-sorted src)
  __half* eap  = (__half*)(srcp + E);        // E*16 halves (dst-sorted fp16 ea)
  // CSR build temporaries (dead before first k_agg) alias bufB:
  int* cnt  = (int*)bufB;
  int* cur  = cnt + N;
  int* bsum = cur + N;

  dim3 b256(256);

  // ---- CSR build (once; edge_index identical across layers) ----
  hipMemsetAsync(cnt, 0, (size_t)N * 4, stream);
  hipMemsetAsync(cur, 0, (size_t)N * 4, stream);
  k_hist<<<E / 256, b256, 0, stream>>>(dst, cnt);
  k_scan_block<<<NB_SCAN, b256, 0, stream>>>(cnt, off, bsum);
  k_scan_bsum<<<1, b256, 0, stream>>>(bsum);
  k_scan_add<<<NB_SCAN, b256, 0, stream>>>(off, bsum);
  k_scatter<<<E / 256, b256, 0, stream>>>(src, dst, off, cur, srcp, eap, edge_attr);

  k_init_vn<<<G * 128 / 256, b256, 0, stream>>>(vn_emb, vn);

  // ---- weight/input fp16 prep ----
  k_tof16<<<(N * 128 / 4 + 255) / 256, b256, 0, stream>>>(x, x16, N * 128 / 4);
  k_wt<<<dim3(64, 1), b256, 0, stream>>>(atom_W, atomWt, 128, 0, 128, 0, 0);
  k_wt<<<dim3(64, 3), b256, 0, stream>>>(conv_W, convWt, 128, 0, 128, 16384, 16384);
  k_wt<<<dim3(128, 3), b256, 0, stream>>>(vn1_W, z2Wt, 256, 128, 256, 65536, 32768);

  // h16 = x16 @ atom_W + atom_b   (fp16 out)
  k_mgemm<true, false, true, false><<<dim3(782, 1), b256, 0, stream>>>(
      x16, atomWt, atom_b, nullptr, nullptr, nullptr, h16, nullptr, 128, N);

  for (int i = 0; i < 3; ++i) {
    k_addvn16<<<12500, b256, 0, stream>>>(h16, vn, batch);
    // hpa16 = h16 + sum_in relu(h16[src] + ea@We + be)   (register-We, fdot2)
    k_agg<<<12500, b256, 0, stream>>>(eap, conv_We + i * 2048, conv_be + i * 128,
                                      off, srcp, h16, hpa16);
    // z = hpa16 @ conv_W[i] + conv_b[i]   (MFMA, fused column stats)
    hipMemsetAsync(stats, 0, 2048, stream);
    k_mgemm<true, false, false, true><<<dim3(782, 1), b256, 0, stream>>>(
        hpa16, convWt + i * 16384, conv_b + i * 128, nullptr, nullptr, z, nullptr,
        stats, 128, N);
    // h16 = relu(bn(z))
    k_bn16<<<12500, b256, 0, stream>>>(z, stats, conv_g + i * 128, conv_beta + i * 128,
                                       h16, 1.f / (float)N);
    // U = vn @ vn1_W[i][:128,:] + vn1_b[i]   (512 distinct rows of vn[batch])
    k_gemm<128, true, false, false><<<dim3(16, 2), b256, 0, stream>>>(
        vn, vn1_W + i * 256 * 256, 256, vn1_b + i * 256, nullptr, nullptr, U, G);
    // z2 = h16 @ vn1_W[i][128:,:] + U[batch]   (MFMA, rowbias, fused stats)
    hipMemsetAsync(stats, 0, 2048, stream);
    hipMemsetAsync(pooled, 0, (size_t)G * 256 * 4, stream);
    k_mgemm<false, true, false, true><<<dim3(782, 2), b256, 0, stream>>>(
        h16, z2Wt + i * 32768, nullptr, U, batch, z2, nullptr, stats, 256, N);
    k_pool<<<(N + 127) / 128, b256, 0, stream>>>(
        z2, stats, vn1_g + i * 256, vn1_beta + i * 256, batch, pooled);
    // zvn = pooled @ vn2_W[i] + vn2_b[i]
    k_gemm<256, true, false, false><<<dim3(16, 1), b256, 0, stream>>>(
        pooled, vn2_W + i * 256 * 128, 128, vn2_b + i * 128, nullptr, nullptr, zvn, G);
    hipMemsetAsync(stats, 0, 2048, stream);
    k_stats<128><<<16, b256, 0, stream>>>(zvn, G, stats);
    k_vnapply<<<G * 128 / 256, b256, 0, stream>>>(
        zvn, stats, vn2_g + i * 128, vn2_beta + i * 128, vn, hgbuf, i);
  }
  // hg2 = relu(hgbuf @ pred_W1 + pred_b1)
  k_gemm<384, true, false, true><<<dim3(16, 3), b256, 0, stream>>>(
      hgbuf, pred_W1, 384, pred_b1, nullptr, nullptr, hg2, G);
  k_pred2<<<G, 64, 0, stream>>>(hg2, pred_W2, pred_b2, (float*)d_out);
}

// Round 6
// 1300.001 us; speedup vs baseline: 1.8052x; 1.0220x over previous
//
#include <hip/hip_runtime.h>
#include <hip/hip_fp16.h>

// Problem constants (fixed by the reference)
constexpr int N = 50000;
constexpr int E = 800000;
constexpr int G = 512;
constexpr int H = 128;
constexpr long long NH = (long long)N * H;   // 6,400,000 elements
constexpr float EPS = 1e-5f;
constexpr int NB_SCAN = 196;                 // ceil(50000/256)

typedef _Float16 f16x8 __attribute__((ext_vector_type(8)));
typedef _Float16 f16x2 __attribute__((ext_vector_type(2)));
typedef float f32x4 __attribute__((ext_vector_type(4)));

// ---------------------------------------------------------------------------
// vn[g][c] = vn_emb[c]
__global__ void k_init_vn(const float* __restrict__ vn_emb, float* __restrict__ vn) {
  int idx = blockIdx.x * 256 + threadIdx.x;   // G*H = 65536 exactly
  vn[idx] = vn_emb[idx & 127];
}

// fp32 -> fp16 bulk convert (float4 -> half2 x2), grid covers n4 exactly
__global__ void k_tof16(const float* __restrict__ in, __half* __restrict__ out, int n4) {
  int i = blockIdx.x * 256 + threadIdx.x;
  if (i >= n4) return;
  float4 v = reinterpret_cast<const float4*>(in)[i];
  __half2* o = reinterpret_cast<__half2*>(out);
  o[i * 2]     = __floats2half2_rn(v.x, v.y);
  o[i * 2 + 1] = __floats2half2_rn(v.z, v.w);
}

// Wt[c][k] = (half) W[(row0+k)*ldw + c], K=128 fixed; one layer per blockIdx.y
__global__ void k_wt(const float* __restrict__ W, __half* __restrict__ Wt,
                     int ldw, int row0, int cols, long long wstride, int wtstride) {
  const float* Wl = W + (long long)blockIdx.y * wstride;
  __half* Wtl = Wt + (long long)blockIdx.y * wtstride;
  int idx = blockIdx.x * 256 + threadIdx.x;   // cols*128, exact multiple of 256
  int k = idx & 127, c = idx >> 7;
  Wtl[c * 128 + k] = __float2half(Wl[(long long)(row0 + k) * ldw + c]);
}

// h16[r][:] += vn[batch[r]][:]  (half2 lanes, grid = N*64/256 = 12500 exact)
__global__ void k_addvn16(__half* __restrict__ h16, const float* __restrict__ vn,
                          const int* __restrict__ batch) {
  int i2 = blockIdx.x * 256 + threadIdx.x;
  int r = i2 >> 6;
  int b = batch[r];
  __half2 hv = reinterpret_cast<__half2*>(h16)[i2];
  float2 vv = reinterpret_cast<const float2*>(vn)[(b << 6) + (i2 & 63)];
  reinterpret_cast<__half2*>(h16)[i2] =
      __floats2half2_rn(__low2float(hv) + vv.x, __high2float(hv) + vv.y);
}

// gstart[g] = lower_bound(batch, g); gstart[G] = N  (batch is sorted)
__global__ void k_gstart(const int* __restrict__ batch, int* __restrict__ gstart) {
  int g = threadIdx.x;   // one block of 512
  int lo = 0, hi = N;
  while (lo < hi) { int mid = (lo + hi) >> 1; if (batch[mid] < g) lo = mid + 1; else hi = mid; }
  gstart[g] = lo;
  if (g == 0) gstart[G] = N;
}

// ---------------------------------------------------------------------------
// CSR build: histogram -> 2-level exclusive scan -> scatter.
// Scatter also permutes edge_attr into dst-order fp16 (eap) so per-layer
// k_agg reads are sequential.
__global__ void k_hist(const int* __restrict__ dst, int* __restrict__ cnt) {
  int e = blockIdx.x * 256 + threadIdx.x;   // grid covers E exactly
  atomicAdd(&cnt[dst[e]], 1);
}

__global__ void k_scan_block(const int* __restrict__ cnt, int* __restrict__ off,
                             int* __restrict__ bsum) {
  __shared__ int s[256];
  int idx = blockIdx.x * 256 + threadIdx.x;
  int v = (idx < N) ? cnt[idx] : 0;
  s[threadIdx.x] = v;
  __syncthreads();
  for (int o = 1; o < 256; o <<= 1) {
    int t = (threadIdx.x >= o) ? s[threadIdx.x - o] : 0;
    __syncthreads();
    s[threadIdx.x] += t;
    __syncthreads();
  }
  if (idx < N) off[idx + 1] = s[threadIdx.x];
  if (threadIdx.x == 255) bsum[blockIdx.x] = s[255];
  if (idx == 0) off[0] = 0;
}

__global__ void k_scan_bsum(int* __restrict__ bsum) {   // single block
  __shared__ int s[256];
  int v = (threadIdx.x < NB_SCAN) ? bsum[threadIdx.x] : 0;
  s[threadIdx.x] = v;
  __syncthreads();
  for (int o = 1; o < 256; o <<= 1) {
    int t = (threadIdx.x >= o) ? s[threadIdx.x - o] : 0;
    __syncthreads();
    s[threadIdx.x] += t;
    __syncthreads();
  }
  if (threadIdx.x < NB_SCAN) bsum[threadIdx.x] = s[threadIdx.x];  // inclusive
}

__global__ void k_scan_add(int* __restrict__ off, const int* __restrict__ bsum) {
  int idx = blockIdx.x * 256 + threadIdx.x;
  if (idx < N && blockIdx.x > 0) off[idx + 1] += bsum[blockIdx.x - 1];
}

__global__ void k_scatter(const int* __restrict__ src, const int* __restrict__ dst,
                          const int* __restrict__ off, int* __restrict__ cur,
                          int* __restrict__ srcp, __half* __restrict__ eap,
                          const float* __restrict__ edge_attr) {
  int e = blockIdx.x * 256 + threadIdx.x;   // grid covers E exactly
  int d = dst[e];
  int p = off[d] + atomicAdd(&cur[d], 1);
  srcp[p] = src[e];
  const float4* ea4 = reinterpret_cast<const float4*>(edge_attr) + e * 4;
  float4 a0 = ea4[0], a1 = ea4[1], a2 = ea4[2], a3 = ea4[3];
  __half2* o = reinterpret_cast<__half2*>(eap + (long long)p * 16);
  o[0] = __floats2half2_rn(a0.x, a0.y);
  o[1] = __floats2half2_rn(a0.z, a0.w);
  o[2] = __floats2half2_rn(a1.x, a1.y);
  o[3] = __floats2half2_rn(a1.z, a1.w);
  o[4] = __floats2half2_rn(a2.x, a2.y);
  o[5] = __floats2half2_rn(a2.z, a2.w);
  o[6] = __floats2half2_rn(a3.x, a3.y);
  o[7] = __floats2half2_rn(a3.z, a3.w);
}

// ---------------------------------------------------------------------------
// CSR aggregation, atomic-free, LDS-free. One 64-lane wave per dst node
// (2 adjacent cols/lane). We panel in registers (packed half2, fdot2).
// eap read as 2x b128 per edge; edge loop unrolled x4 for 4 gather chains.
// hpa16[d] = h16[d] + sum_{e in in(d)} relu(h16[src[e]] + ea[e] @ We + be)
__global__ __launch_bounds__(256) void k_agg(
    const __half* __restrict__ eap, const float* __restrict__ We,
    const float* __restrict__ be, const int* __restrict__ off,
    const int* __restrict__ srcp, const __half* __restrict__ h16,
    __half* __restrict__ hpa16) {
  int tid = threadIdx.x;
  int lane = tid & 63;
  int c0 = lane * 2;
  f16x2 wc0[8], wc1[8];
#pragma unroll
  for (int kk = 0; kk < 8; ++kk) {
    f16x2 w0, w1;
    w0[0] = (_Float16)We[(2 * kk) * 128 + c0];
    w0[1] = (_Float16)We[(2 * kk + 1) * 128 + c0];
    w1[0] = (_Float16)We[(2 * kk) * 128 + c0 + 1];
    w1[1] = (_Float16)We[(2 * kk + 1) * 128 + c0 + 1];
    wc0[kk] = w0; wc1[kk] = w1;
  }
  float2 bev = reinterpret_cast<const float2*>(be)[lane];
  int d = blockIdx.x * 4 + (tid >> 6);   // grid = 12500 -> covers N exactly
  int j0 = off[d], j1 = off[d + 1];
  const __half2* h2 = reinterpret_cast<const __half2*>(h16);
  const int4* e4 = reinterpret_cast<const int4*>(eap);
  float a0 = 0.f, a1 = 0.f, b0 = 0.f, b1 = 0.f;
  float p0 = 0.f, p1 = 0.f, q0 = 0.f, q1 = 0.f;
  int j = j0;
#define EDGE(J, A0, A1) do {                                                   \
    int s_ = srcp[(J)];                                                        \
    __half2 hv_ = h2[(long long)s_ * 64 + lane];                               \
    int4 lo_ = e4[2 * (J)], hi_ = e4[2 * (J) + 1];                             \
    float ev0_ = bev.x, ev1_ = bev.y;                                          \
    int w_[8] = {lo_.x, lo_.y, lo_.z, lo_.w, hi_.x, hi_.y, hi_.z, hi_.w};      \
    _Pragma("unroll")                                                          \
    for (int kk = 0; kk < 8; ++kk) {                                           \
      f16x2 ea_ = __builtin_bit_cast(f16x2, w_[kk]);                           \
      ev0_ = __builtin_amdgcn_fdot2(ea_, wc0[kk], ev0_, false);                \
      ev1_ = __builtin_amdgcn_fdot2(ea_, wc1[kk], ev1_, false);                \
    }                                                                          \
    A0 += fmaxf(__low2float(hv_) + ev0_, 0.f);                                 \
    A1 += fmaxf(__high2float(hv_) + ev1_, 0.f);                                \
  } while (0)
  for (; j + 3 < j1; j += 4) {
    EDGE(j, a0, a1);
    EDGE(j + 1, b0, b1);
    EDGE(j + 2, p0, p1);
    EDGE(j + 3, q0, q1);
  }
  for (; j < j1; ++j) EDGE(j, a0, a1);
#undef EDGE
  a0 += b0 + p0 + q0; a1 += b1 + p1 + q1;
  __half2 hd = h2[(long long)d * 64 + lane];
  reinterpret_cast<__half2*>(hpa16)[(long long)d * 64 + lane] =
      __floats2half2_rn(__low2float(hd) + a0, __high2float(hd) + a1);
}

// ---------------------------------------------------------------------------
// fp16 MFMA GEMM, K=128 fixed. C[M x ldc] fp32 (or fp16 when OUT_F16).
// A [M][128] f16 row-major; Bt [ldc][128] f16 with Bt[c][k] = W[k][c].
// Block: 64 rows x 128 cols, 4 waves in 2x2, wave tile 32x64.
// STATS: fused column sum/sumsq -> atomicAdd into stats[0:ldc], stats[ldc:2ldc]
// (stats must be pre-zeroed; only rows < M contribute).
// bias2 (optional, with HAS_BIAS): extra column bias (e.g. vn_emb fold).
template<bool HAS_BIAS, bool HAS_ROWBIAS, bool OUT_F16, bool STATS>
__global__ __launch_bounds__(256) void k_mgemm(
    const __half* __restrict__ A, const __half* __restrict__ Bt,
    const float* __restrict__ bias, const float* __restrict__ bias2,
    const float* __restrict__ rowbias, const int* __restrict__ batch,
    float* __restrict__ Cf, __half* __restrict__ Ch,
    float* __restrict__ stats, int ldc, int M) {
  __shared__ _Float16 Ash[64][136];    // +8 pad: row stride 272 B = 17*16 B
  __shared__ _Float16 Bsh[128][136];
  int tid = threadIdx.x;
  int m0 = blockIdx.x * 64;
  int c0 = blockIdx.y * 128;
  // stage A: 64 rows x 16 chunks(8 f16) = 1024 chunks
#pragma unroll
  for (int it = 0; it < 4; ++it) {
    int idx = it * 256 + tid;
    int r = idx >> 4, ck = idx & 15;
    f16x8 v = {0, 0, 0, 0, 0, 0, 0, 0};
    if (m0 + r < M)
      v = *reinterpret_cast<const f16x8*>(A + (((long long)(m0 + r)) << 7) + ck * 8);
    *reinterpret_cast<f16x8*>(&Ash[r][ck * 8]) = v;
  }
  // stage B: 128 rows x 16 chunks = 2048 chunks
#pragma unroll
  for (int it = 0; it < 8; ++it) {
    int idx = it * 256 + tid;
    int r = idx >> 4, ck = idx & 15;
    f16x8 v = *reinterpret_cast<const f16x8*>(Bt + (((long long)(c0 + r)) << 7) + ck * 8);
    *reinterpret_cast<f16x8*>(&Bsh[r][ck * 8]) = v;
  }
  __syncthreads();

  int wid = tid >> 6, lane = tid & 63;
  int wr = wid >> 1, wc = wid & 1;        // 2x2 wave grid, wave tile 32x64
  int lrow = lane & 15;
  int lk = (lane >> 4) * 8;
  f32x4 acc[2][4];
#pragma unroll
  for (int fm = 0; fm < 2; ++fm)
#pragma unroll
    for (int fn = 0; fn < 4; ++fn) acc[fm][fn] = (f32x4){0.f, 0.f, 0.f, 0.f};

#pragma unroll
  for (int kk = 0; kk < 4; ++kk) {
    f16x8 af[2], bf[4];
#pragma unroll
    for (int fm = 0; fm < 2; ++fm)
      af[fm] = *reinterpret_cast<const f16x8*>(&Ash[wr * 32 + fm * 16 + lrow][kk * 32 + lk]);
#pragma unroll
    for (int fn = 0; fn < 4; ++fn)
      bf[fn] = *reinterpret_cast<const f16x8*>(&Bsh[wc * 64 + fn * 16 + lrow][kk * 32 + lk]);
#pragma unroll
    for (int fm = 0; fm < 2; ++fm)
#pragma unroll
      for (int fn = 0; fn < 4; ++fn)
        acc[fm][fn] = __builtin_amdgcn_mfma_f32_16x16x32_f16(af[fm], bf[fn], acc[fm][fn], 0, 0, 0);
  }

  // epilogue (+ optional fused column stats)
  float ss[4], ss2[4];
#pragma unroll
  for (int fn = 0; fn < 4; ++fn) { ss[fn] = 0.f; ss2[fn] = 0.f; }
#pragma unroll
  for (int fn = 0; fn < 4; ++fn) {
    int col = c0 + wc * 64 + fn * 16 + lrow;
    float bb = HAS_BIAS ? bias[col] : 0.f;
    if (HAS_BIAS && bias2 != nullptr) bb += bias2[col];
#pragma unroll
    for (int fm = 0; fm < 2; ++fm) {
      int grb = m0 + wr * 32 + fm * 16 + (lane >> 4) * 4;
#pragma unroll
      for (int j = 0; j < 4; ++j) {
        int gr = grb + j;
        if (gr < M) {
          float v = acc[fm][fn][j] + bb;
          if (HAS_ROWBIAS)
            v += rowbias[(long long)batch[gr] * ldc + col];
          if (STATS) { ss[fn] += v; ss2[fn] += v * v; }
          if (OUT_F16)
            Ch[(long long)gr * ldc + col] = __float2half(v);
          else
            Cf[(long long)gr * ldc + col] = v;
        }
      }
    }
  }
  if (STATS) {
    __shared__ float sred[2][4][4][16];   // [s|s2][wid][fn][lrow]
#pragma unroll
    for (int fn = 0; fn < 4; ++fn) {
      float s = ss[fn], s2 = ss2[fn];
      s += __shfl_xor(s, 16);  s += __shfl_xor(s, 32);
      s2 += __shfl_xor(s2, 16); s2 += __shfl_xor(s2, 32);
      if (lane < 16) { sred[0][wid][fn][lane] = s; sred[1][wid][fn][lane] = s2; }
    }
    __syncthreads();
    if (wr == 0 && lane < 16) {           // waves 0,1 combine with waves 2,3
#pragma unroll
      for (int fn = 0; fn < 4; ++fn) {
        int col = c0 + wc * 64 + fn * 16 + lane;
        atomicAdd(&stats[col],       sred[0][wid][fn][lane] + sred[0][wid + 2][fn][lane]);
        atomicAdd(&stats[ldc + col], sred[1][wid][fn][lane] + sred[1][wid + 2][fn][lane]);
      }
    }
  }
}

// ---------------------------------------------------------------------------
// Generic fp32 vector GEMM for the small (G-row) matmuls.
// STATS: fused column sum/sumsq into stats[0:128], stats[ldw:ldw+128] via LDS.
template<int K, bool HAS_BIAS, bool HAS_ROWBIAS, bool RELU, bool STATS>
__global__ __launch_bounds__(256) void k_gemm(
    const float* __restrict__ A1,
    const float* __restrict__ W, int ldw,
    const float* __restrict__ bias,
    const float* __restrict__ rowbias, const int* __restrict__ batch,
    float* __restrict__ C, float* __restrict__ stats, int M) {
  __shared__ float As[32 * K];
  constexpr int K4 = K / 4;
  int tid = threadIdx.x;
  int m0 = blockIdx.x * 32;
#pragma unroll
  for (int it = 0; it < K / 32; ++it) {
    int e4 = it * 256 + tid;
    int r = e4 / K4;
    int k4 = e4 % K4;
    int gr = m0 + r;
    float4 v = make_float4(0.f, 0.f, 0.f, 0.f);
    if (gr < M) v = reinterpret_cast<const float4*>(A1)[(long long)gr * K4 + k4];
    reinterpret_cast<float4*>(As)[e4] = v;
  }
  __shared__ float cs[128], cs2[128];
  if (STATS && tid < 128) { cs[tid] = 0.f; cs2[tid] = 0.f; }
  __syncthreads();

  int cg = tid & 31;
  int rg = tid >> 5;
  int col = blockIdx.y * 128 + cg * 4;
  float4 acc[4];
#pragma unroll
  for (int j = 0; j < 4; ++j) acc[j] = make_float4(0.f, 0.f, 0.f, 0.f);
  const float4* W4 = reinterpret_cast<const float4*>(W);
  const float4* As4 = reinterpret_cast<const float4*>(As);
#pragma unroll 8
  for (int k = 0; k < K; k += 4) {
    float4 w0 = W4[((k + 0) * ldw + col) >> 2];
    float4 w1 = W4[((k + 1) * ldw + col) >> 2];
    float4 w2 = W4[((k + 2) * ldw + col) >> 2];
    float4 w3 = W4[((k + 3) * ldw + col) >> 2];
#pragma unroll
    for (int j = 0; j < 4; ++j) {
      float4 a = As4[(rg + j * 8) * K4 + (k >> 2)];
      acc[j].x += a.x * w0.x + a.y * w1.x + a.z * w2.x + a.w * w3.x;
      acc[j].y += a.x * w0.y + a.y * w1.y + a.z * w2.y + a.w * w3.y;
      acc[j].z += a.x * w0.z + a.y * w1.z + a.z * w2.z + a.w * w3.z;
      acc[j].w += a.x * w0.w + a.y * w1.w + a.z * w2.w + a.w * w3.w;
    }
  }
  float4 bb = make_float4(0.f, 0.f, 0.f, 0.f);
  if (HAS_BIAS) bb = reinterpret_cast<const float4*>(bias)[blockIdx.y * 32 + cg];
  float ps[4] = {0.f, 0.f, 0.f, 0.f}, ps2[4] = {0.f, 0.f, 0.f, 0.f};
#pragma unroll
  for (int j = 0; j < 4; ++j) {
    int gr = m0 + rg + j * 8;
    if (gr < M) {
      float4 v = acc[j];
      v.x += bb.x; v.y += bb.y; v.z += bb.z; v.w += bb.w;
      if (HAS_ROWBIAS) {
        int b = batch[gr];
        float4 rb = reinterpret_cast<const float4*>(rowbias)[((long long)b * ldw + col) >> 2];
        v.x += rb.x; v.y += rb.y; v.z += rb.z; v.w += rb.w;
      }
      if (RELU) {
        v.x = fmaxf(v.x, 0.f); v.y = fmaxf(v.y, 0.f);
        v.z = fmaxf(v.z, 0.f); v.w = fmaxf(v.w, 0.f);
      }
      if (STATS) {
        ps[0] += v.x; ps2[0] += v.x * v.x;
        ps[1] += v.y; ps2[1] += v.y * v.y;
        ps[2] += v.z; ps2[2] += v.z * v.z;
        ps[3] += v.w; ps2[3] += v.w * v.w;
      }
      reinterpret_cast<float4*>(C)[((long long)gr * ldw + col) >> 2] = v;
    }
  }
  if (STATS) {
#pragma unroll
    for (int jc = 0; jc < 4; ++jc) {
      atomicAdd(&cs[cg * 4 + jc], ps[jc]);
      atomicAdd(&cs2[cg * 4 + jc], ps2[jc]);
    }
    __syncthreads();
    if (tid < 128) {
      atomicAdd(&stats[blockIdx.y * 128 + tid], cs[tid]);
      atomicAdd(&stats[ldw + blockIdx.y * 128 + tid], cs2[tid]);
    }
  }
}

// ---------------------------------------------------------------------------
// h16 = (half) relu(bn(z16)); half2 lanes, grid = N*64/256 = 12500 exact
__global__ void k_bn16(const __half* __restrict__ X16, const float* __restrict__ stats,
                       const float* __restrict__ gam, const float* __restrict__ beta,
                       __half* __restrict__ out16, float invM) {
  int i2 = blockIdx.x * 256 + threadIdx.x;
  int c = (i2 & 63) * 2;
  __half2 xv = reinterpret_cast<const __half2*>(X16)[i2];
  float m0 = stats[c] * invM;
  float v0 = stats[128 + c] * invM - m0 * m0;
  float m1 = stats[c + 1] * invM;
  float v1 = stats[128 + c + 1] * invM - m1 * m1;
  float r0 = fmaxf((__low2float(xv) - m0) * rsqrtf(v0 + EPS) * gam[c] + beta[c], 0.f);
  float r1 = fmaxf((__high2float(xv) - m1) * rsqrtf(v1 + EPS) * gam[c + 1] + beta[c + 1], 0.f);
  reinterpret_cast<__half2*>(out16)[i2] = __floats2half2_rn(r0, r1);
}

// pooled[g][c] = sum over graph-g rows of relu(bn(z2_16[r][c])).
// Per-graph blocks via gstart (batch sorted): atomic-free, no pre-zero needed.
__global__ void k_pool(const __half* __restrict__ z2_16, const float* __restrict__ stats,
                       const float* __restrict__ gam, const float* __restrict__ beta,
                       const int* __restrict__ gstart, float* __restrict__ pooled) {
  int g = blockIdx.x;
  int c = blockIdx.y * 128 + threadIdx.x;   // grid (G,2) x 128 threads
  const float invM = 1.f / (float)N;
  float mean = stats[c] * invM;
  float var = stats[256 + c] * invM - mean * mean;
  float scale = rsqrtf(var + EPS) * gam[c];
  float shift = beta[c] - mean * scale;
  int r0 = gstart[g], r1 = gstart[g + 1];
  float acc = 0.f;
  for (int r = r0; r < r1; ++r) {
    float v = __half2float(z2_16[(long long)r * 256 + c]);
    acc += fmaxf(v * scale + shift, 0.f);
  }
  pooled[g * 256 + c] = acc;
}

// vn = relu(bn(zvn)); also write into hg concat buffer at layer offset
__global__ void k_vnapply(const float* __restrict__ zvn, const float* __restrict__ stats,
                          const float* __restrict__ gam, const float* __restrict__ beta,
                          float* __restrict__ vn, float* __restrict__ hgbuf, int layer) {
  int idx = blockIdx.x * 256 + threadIdx.x;  // G*H = 65536
  int c = idx & 127;
  int g = idx >> 7;
  const float invM = 1.f / (float)G;
  float mean = stats[c] * invM;
  float var = stats[128 + c] * invM - mean * mean;
  float v = fmaxf((zvn[idx] - mean) * rsqrtf(var + EPS) * gam[c] + beta[c], 0.f);
  vn[idx] = v;
  hgbuf[g * 384 + layer * 128 + c] = v;
}

// out[g] = hg2[g] @ pred_W2 + b2   (one wave per graph)
__global__ void k_pred2(const float* __restrict__ hg2, const float* __restrict__ W2,
                        const float* __restrict__ b2, float* __restrict__ out) {
  int g = blockIdx.x;
  int lane = threadIdx.x;
  float s = 0.f;
  for (int k = lane; k < 384; k += 64) s += hg2[g * 384 + k] * W2[k];
  for (int off = 32; off; off >>= 1) s += __shfl_down(s, off);
  if (lane == 0) out[g] = s + b2[0];
}

// ---------------------------------------------------------------------------
extern "C" void kernel_launch(void* const* d_in, const int* in_sizes, int n_in,
                              void* d_out, int out_size, void* d_ws, size_t ws_size,
                              hipStream_t stream) {
  const float* x         = (const float*)d_in[0];
  const float* edge_attr = (const float*)d_in[1];
  const float* atom_W    = (const float*)d_in[2];
  const float* atom_b    = (const float*)d_in[3];
  const float* vn_emb    = (const float*)d_in[4];
  const float* conv_We   = (const float*)d_in[5];
  const float* conv_be   = (const float*)d_in[6];
  const float* conv_W    = (const float*)d_in[7];
  const float* conv_b    = (const float*)d_in[8];
  const float* conv_g    = (const float*)d_in[9];
  const float* conv_beta = (const float*)d_in[10];
  const float* vn1_W     = (const float*)d_in[11];
  const float* vn1_b     = (const float*)d_in[12];
  const float* vn1_g     = (const float*)d_in[13];
  const float* vn1_beta  = (const float*)d_in[14];
  const float* vn2_W     = (const float*)d_in[15];
  const float* vn2_b     = (const float*)d_in[16];
  const float* vn2_g     = (const float*)d_in[17];
  const float* vn2_beta  = (const float*)d_in[18];
  const float* pred_W1   = (const float*)d_in[19];
  const float* pred_b1   = (const float*)d_in[20];
  const float* pred_W2   = (const float*)d_in[21];
  const float* pred_b2   = (const float*)d_in[22];
  const int*   eidx      = (const int*)d_in[23];
  const int*   batch     = (const int*)d_in[24];
  const int* src = eidx;
  const int* dst = eidx + E;

  // Workspace layout (units: 4-byte slots). Total ~24.1M slots = ~96.5 MB.
  float* ws    = (float*)d_ws;
  __half* h16  = (__half*)ws;                  // N*128 halves
  float* bufB  = ws + NH / 2;                  // 2*NH slots
  __half* hpa16= (__half*)bufB;                // N*128 halves  [B 0 .. NH/2)
  __half* z16  = (__half*)(bufB + NH / 2);     // N*128 halves  [B NH/2 .. NH)
  __half* x16  = z16;                          // alias (dead before conv gemm)
  __half* z2_16= (__half*)(bufB + NH);         // N*256 halves  [B NH .. 2NH)
  float* smallz= bufB + 2 * NH;
  float* U     = smallz;                       // G*256
  float* pooled= U + G * 256;                  // G*256
  float* zvn   = pooled + G * 256;             // G*128
  float* vn    = zvn + G * 128;                // G*128
  float* hgbuf = vn + G * 128;                 // G*384
  float* hg2   = hgbuf + G * 384;              // G*384
  float* statsz= hg2 + G * 384;                // 3*1024 (per-layer slices)
  int*   gstart= (int*)(statsz + 3 * 1024);    // G+1 (pad 516)
  __half* atomWt = (__half*)(gstart + 516);    // 128*128 halves
  __half* convWt = atomWt + 16384;             // 3 * 128*128
  __half* z2Wt   = convWt + 3 * 16384;         // 3 * 256*128
  int*  off    = (int*)(z2Wt + 3 * 32768);     // N+1 (padded 50002)
  int*  srcp   = off + 50002;                  // E ints (dst-sorted src)
  __half* eap  = (__half*)(srcp + E);          // E*16 halves (dst-sorted fp16 ea)
  // CSR build temporaries (dead before first k_agg) alias bufB:
  int* cnt  = (int*)bufB;
  int* cur  = cnt + N;
  int* bsum = cur + N;

  dim3 b256(256);

  // ---- CSR build (once; edge_index identical across layers) ----
  hipMemsetAsync(cnt, 0, (size_t)N * 4, stream);
  hipMemsetAsync(cur, 0, (size_t)N * 4, stream);
  hipMemsetAsync(statsz, 0, 3 * 1024 * 4, stream);
  k_hist<<<E / 256, b256, 0, stream>>>(dst, cnt);
  k_scan_block<<<NB_SCAN, b256, 0, stream>>>(cnt, off, bsum);
  k_scan_bsum<<<1, b256, 0, stream>>>(bsum);
  k_scan_add<<<NB_SCAN, b256, 0, stream>>>(off, bsum);
  k_scatter<<<E / 256, b256, 0, stream>>>(src, dst, off, cur, srcp, eap, edge_attr);
  k_gstart<<<1, G, 0, stream>>>(batch, gstart);

  k_init_vn<<<G * 128 / 256, b256, 0, stream>>>(vn_emb, vn);

  // ---- weight/input fp16 prep ----
  k_tof16<<<(N * 128 / 4 + 255) / 256, b256, 0, stream>>>(x, x16, N * 128 / 4);
  k_wt<<<dim3(64, 1), b256, 0, stream>>>(atom_W, atomWt, 128, 0, 128, 0, 0);
  k_wt<<<dim3(64, 3), b256, 0, stream>>>(conv_W, convWt, 128, 0, 128, 16384, 16384);
  k_wt<<<dim3(128, 3), b256, 0, stream>>>(vn1_W, z2Wt, 256, 128, 256, 65536, 32768);

  // h16 = x16 @ atom_W + (atom_b + vn_emb)   (layer-0 addvn folded: vn0 is broadcast)
  k_mgemm<true, false, true, false><<<dim3(782, 1), b256, 0, stream>>>(
      x16, atomWt, atom_b, vn_emb, nullptr, nullptr, nullptr, h16, nullptr, 128, N);

  for (int i = 0; i < 3; ++i) {
    float* SZ = statsz + i * 1024;   // conv: +0 (256), z2: +256 (512), zvn: +768 (256)
    if (i > 0) k_addvn16<<<12500, b256, 0, stream>>>(h16, vn, batch);
    // hpa16 = h16 + sum_in relu(h16[src] + ea@We + be)
    k_agg<<<12500, b256, 0, stream>>>(eap, conv_We + i * 2048, conv_be + i * 128,
                                      off, srcp, h16, hpa16);
    // z16 = hpa16 @ conv_W[i] + conv_b[i]   (MFMA, fp16 out, fused stats)
    k_mgemm<true, false, true, true><<<dim3(782, 1), b256, 0, stream>>>(
        hpa16, convWt + i * 16384, conv_b + i * 128, nullptr, nullptr, nullptr,
        nullptr, z16, SZ, 128, N);
    // h16 = relu(bn(z16))
    k_bn16<<<12500, b256, 0, stream>>>(z16, SZ, conv_g + i * 128, conv_beta + i * 128,
                                       h16, 1.f / (float)N);
    // U = vn @ vn1_W[i][:128,:] + vn1_b[i]   (512 distinct rows of vn[batch])
    k_gemm<128, true, false, false, false><<<dim3(16, 2), b256, 0, stream>>>(
        vn, vn1_W + i * 256 * 256, 256, vn1_b + i * 256, nullptr, nullptr, U, nullptr, G);
    // z2_16 = h16 @ vn1_W[i][128:,:] + U[batch]   (MFMA, fp16 out, fused stats)
    k_mgemm<false, true, true, true><<<dim3(782, 2), b256, 0, stream>>>(
        h16, z2Wt + i * 32768, nullptr, nullptr, U, batch, nullptr, z2_16,
        SZ + 256, 256, N);
    // pooled[g] = sum relu(bn(z2_16))   (per-graph, atomic-free)
    k_pool<<<dim3(G, 2), dim3(128), 0, stream>>>(
        z2_16, SZ + 256, vn1_g + i * 256, vn1_beta + i * 256, gstart, pooled);
    // zvn = pooled @ vn2_W[i] + vn2_b[i]  (fused stats)
    k_gemm<256, true, false, false, true><<<dim3(16, 1), b256, 0, stream>>>(
        pooled, vn2_W + i * 256 * 128, 128, vn2_b + i * 128, nullptr, nullptr,
        zvn, SZ + 768, G);
    k_vnapply<<<G * 128 / 256, b256, 0, stream>>>(
        zvn, SZ + 768, vn2_g + i * 128, vn2_beta + i * 128, vn, hgbuf, i);
  }
  // hg2 = relu(hgbuf @ pred_W1 + pred_b1)
  k_gemm<384, true, false, true, false><<<dim3(16, 3), b256, 0, stream>>>(
      hgbuf, pred_W1, 384, pred_b1, nullptr, nullptr, hg2, nullptr, G);
  k_pred2<<<G, 64, 0, stream>>>(hg2, pred_W2, pred_b2, (float*)d_out);
}

// Round 8
// 1287.419 us; speedup vs baseline: 1.8229x; 1.0098x over previous
//
#include <hip/hip_runtime.h>
#include <hip/hip_fp16.h>

// Problem constants (fixed by the reference)
constexpr int N = 50000;
constexpr int E = 800000;
constexpr int G = 512;
constexpr int H = 128;
constexpr long long NH = (long long)N * H;   // 6,400,000 elements
constexpr float EPS = 1e-5f;
constexpr int NB_SCAN = 196;                 // ceil(50000/256)

typedef _Float16 f16x8 __attribute__((ext_vector_type(8)));
typedef _Float16 f16x2 __attribute__((ext_vector_type(2)));
typedef float f32x4 __attribute__((ext_vector_type(4)));

// ---------------------------------------------------------------------------
// vn[g][c] = vn_emb[c]
__global__ void k_init_vn(const float* __restrict__ vn_emb, float* __restrict__ vn) {
  int idx = blockIdx.x * 256 + threadIdx.x;   // G*H = 65536 exactly
  vn[idx] = vn_emb[idx & 127];
}

// fp32 -> fp16 bulk convert (float4 -> half2 x2), grid covers n4 exactly
__global__ void k_tof16(const float* __restrict__ in, __half* __restrict__ out, int n4) {
  int i = blockIdx.x * 256 + threadIdx.x;
  if (i >= n4) return;
  float4 v = reinterpret_cast<const float4*>(in)[i];
  __half2* o = reinterpret_cast<__half2*>(out);
  o[i * 2]     = __floats2half2_rn(v.x, v.y);
  o[i * 2 + 1] = __floats2half2_rn(v.z, v.w);
}

// Wt[c][k] = (half) W[(row0+k)*ldw + c], K=128 fixed; one layer per blockIdx.y
__global__ void k_wt(const float* __restrict__ W, __half* __restrict__ Wt,
                     int ldw, int row0, int cols, long long wstride, int wtstride) {
  const float* Wl = W + (long long)blockIdx.y * wstride;
  __half* Wtl = Wt + (long long)blockIdx.y * wtstride;
  int idx = blockIdx.x * 256 + threadIdx.x;   // cols*128, exact multiple of 256
  int k = idx & 127, c = idx >> 7;
  Wtl[c * 128 + k] = __float2half(Wl[(long long)(row0 + k) * ldw + c]);
}

// h16[r][:] += vn[batch[r]][:]  (half2 lanes, grid = N*64/256 = 12500 exact)
__global__ void k_addvn16(__half* __restrict__ h16, const float* __restrict__ vn,
                          const int* __restrict__ batch) {
  int i2 = blockIdx.x * 256 + threadIdx.x;
  int r = i2 >> 6;
  int b = batch[r];
  __half2 hv = reinterpret_cast<__half2*>(h16)[i2];
  float2 vv = reinterpret_cast<const float2*>(vn)[(b << 6) + (i2 & 63)];
  reinterpret_cast<__half2*>(h16)[i2] =
      __floats2half2_rn(__low2float(hv) + vv.x, __high2float(hv) + vv.y);
}

// gstart[g] = lower_bound(batch, g); gstart[G] = N  (batch is sorted)
__global__ void k_gstart(const int* __restrict__ batch, int* __restrict__ gstart) {
  int g = threadIdx.x;   // one block of 512
  int lo = 0, hi = N;
  while (lo < hi) { int mid = (lo + hi) >> 1; if (batch[mid] < g) lo = mid + 1; else hi = mid; }
  gstart[g] = lo;
  if (g == 0) gstart[G] = N;
}

// ---------------------------------------------------------------------------
// CSR build: histogram -> 2-level exclusive scan -> scatter.
// Scatter also permutes edge_attr into dst-order fp16 (eap) so per-layer
// k_agg reads are sequential, and pre-scales src to a half2-index (src*64).
__global__ void k_hist(const int* __restrict__ dst, int* __restrict__ cnt) {
  int e = blockIdx.x * 256 + threadIdx.x;   // grid covers E exactly
  atomicAdd(&cnt[dst[e]], 1);
}

__global__ void k_scan_block(const int* __restrict__ cnt, int* __restrict__ off,
                             int* __restrict__ bsum) {
  __shared__ int s[256];
  int idx = blockIdx.x * 256 + threadIdx.x;
  int v = (idx < N) ? cnt[idx] : 0;
  s[threadIdx.x] = v;
  __syncthreads();
  for (int o = 1; o < 256; o <<= 1) {
    int t = (threadIdx.x >= o) ? s[threadIdx.x - o] : 0;
    __syncthreads();
    s[threadIdx.x] += t;
    __syncthreads();
  }
  if (idx < N) off[idx + 1] = s[threadIdx.x];
  if (threadIdx.x == 255) bsum[blockIdx.x] = s[255];
  if (idx == 0) off[0] = 0;
}

__global__ void k_scan_bsum(int* __restrict__ bsum) {   // single block
  __shared__ int s[256];
  int v = (threadIdx.x < NB_SCAN) ? bsum[threadIdx.x] : 0;
  s[threadIdx.x] = v;
  __syncthreads();
  for (int o = 1; o < 256; o <<= 1) {
    int t = (threadIdx.x >= o) ? s[threadIdx.x - o] : 0;
    __syncthreads();
    s[threadIdx.x] += t;
    __syncthreads();
  }
  if (threadIdx.x < NB_SCAN) bsum[threadIdx.x] = s[threadIdx.x];  // inclusive
}

__global__ void k_scan_add(int* __restrict__ off, const int* __restrict__ bsum) {
  int idx = blockIdx.x * 256 + threadIdx.x;
  if (idx < N && blockIdx.x > 0) off[idx + 1] += bsum[blockIdx.x - 1];
}

__global__ void k_scatter(const int* __restrict__ src, const int* __restrict__ dst,
                          const int* __restrict__ off, int* __restrict__ cur,
                          int* __restrict__ srcp, __half* __restrict__ eap,
                          const float* __restrict__ edge_attr) {
  int e = blockIdx.x * 256 + threadIdx.x;   // grid covers E exactly
  int d = dst[e];
  int p = off[d] + atomicAdd(&cur[d], 1);
  srcp[p] = src[e] * 64;                    // pre-scaled half2 index
  const float4* ea4 = reinterpret_cast<const float4*>(edge_attr) + e * 4;
  float4 a0 = ea4[0], a1 = ea4[1], a2 = ea4[2], a3 = ea4[3];
  __half2* o = reinterpret_cast<__half2*>(eap + (long long)p * 16);
  o[0] = __floats2half2_rn(a0.x, a0.y);
  o[1] = __floats2half2_rn(a0.z, a0.w);
  o[2] = __floats2half2_rn(a1.x, a1.y);
  o[3] = __floats2half2_rn(a1.z, a1.w);
  o[4] = __floats2half2_rn(a2.x, a2.y);
  o[5] = __floats2half2_rn(a2.z, a2.w);
  o[6] = __floats2half2_rn(a3.x, a3.y);
  o[7] = __floats2half2_rn(a3.z, a3.w);
}

// ---------------------------------------------------------------------------
// CSR aggregation, atomic-free, LDS-free, all-32-bit indexing. One 64-lane
// wave per dst node (2 adjacent cols/lane). We panel in registers (fdot2).
// Grid covers nodes [d0, d0+4*gridDim.x).
// hpa16[d] = h16[d] + sum_{e in in(d)} relu(h16[src[e]] + ea[e] @ We + be)
__global__ __launch_bounds__(256) void k_agg(
    const __half* __restrict__ eap, const float* __restrict__ We,
    const float* __restrict__ be, const int* __restrict__ off,
    const int* __restrict__ srcp, const __half* __restrict__ h16,
    __half* __restrict__ hpa16, int d0) {
  int tid = threadIdx.x;
  int lane = tid & 63;
  int c0 = lane * 2;
  f16x2 wc0[8], wc1[8];
#pragma unroll
  for (int kk = 0; kk < 8; ++kk) {
    f16x2 w0, w1;
    w0[0] = (_Float16)We[(2 * kk) * 128 + c0];
    w0[1] = (_Float16)We[(2 * kk + 1) * 128 + c0];
    w1[0] = (_Float16)We[(2 * kk) * 128 + c0 + 1];
    w1[1] = (_Float16)We[(2 * kk + 1) * 128 + c0 + 1];
    wc0[kk] = w0; wc1[kk] = w1;
  }
  float2 bev = reinterpret_cast<const float2*>(be)[lane];
  int d = d0 + blockIdx.x * 4 + (tid >> 6);
  int j0 = off[d], j1 = off[d + 1];
  const __half2* h2 = reinterpret_cast<const __half2*>(h16);
  const int4* e4 = reinterpret_cast<const int4*>(eap);
  float a0 = 0.f, a1 = 0.f, b0 = 0.f, b1 = 0.f;
  float p0 = 0.f, p1 = 0.f, q0 = 0.f, q1 = 0.f;
  int j = j0;
#define EDGE(J, A0, A1) do {                                                   \
    int s_ = srcp[(J)];                                                        \
    __half2 hv_ = h2[s_ + lane];                                               \
    int4 lo_ = e4[2 * (J)], hi_ = e4[2 * (J) + 1];                             \
    float ev0_ = bev.x, ev1_ = bev.y;                                          \
    ev0_ = __builtin_amdgcn_fdot2(__builtin_bit_cast(f16x2, lo_.x), wc0[0], ev0_, false); \
    ev1_ = __builtin_amdgcn_fdot2(__builtin_bit_cast(f16x2, lo_.x), wc1[0], ev1_, false); \
    ev0_ = __builtin_amdgcn_fdot2(__builtin_bit_cast(f16x2, lo_.y), wc0[1], ev0_, false); \
    ev1_ = __builtin_amdgcn_fdot2(__builtin_bit_cast(f16x2, lo_.y), wc1[1], ev1_, false); \
    ev0_ = __builtin_amdgcn_fdot2(__builtin_bit_cast(f16x2, lo_.z), wc0[2], ev0_, false); \
    ev1_ = __builtin_amdgcn_fdot2(__builtin_bit_cast(f16x2, lo_.z), wc1[2], ev1_, false); \
    ev0_ = __builtin_amdgcn_fdot2(__builtin_bit_cast(f16x2, lo_.w), wc0[3], ev0_, false); \
    ev1_ = __builtin_amdgcn_fdot2(__builtin_bit_cast(f16x2, lo_.w), wc1[3], ev1_, false); \
    ev0_ = __builtin_amdgcn_fdot2(__builtin_bit_cast(f16x2, hi_.x), wc0[4], ev0_, false); \
    ev1_ = __builtin_amdgcn_fdot2(__builtin_bit_cast(f16x2, hi_.x), wc1[4], ev1_, false); \
    ev0_ = __builtin_amdgcn_fdot2(__builtin_bit_cast(f16x2, hi_.y), wc0[5], ev0_, false); \
    ev1_ = __builtin_amdgcn_fdot2(__builtin_bit_cast(f16x2, hi_.y), wc1[5], ev1_, false); \
    ev0_ = __builtin_amdgcn_fdot2(__builtin_bit_cast(f16x2, hi_.z), wc0[6], ev0_, false); \
    ev1_ = __builtin_amdgcn_fdot2(__builtin_bit_cast(f16x2, hi_.z), wc1[6], ev1_, false); \
    ev0_ = __builtin_amdgcn_fdot2(__builtin_bit_cast(f16x2, hi_.w), wc0[7], ev0_, false); \
    ev1_ = __builtin_amdgcn_fdot2(__builtin_bit_cast(f16x2, hi_.w), wc1[7], ev1_, false); \
    A0 += fmaxf(__low2float(hv_) + ev0_, 0.f);                                 \
    A1 += fmaxf(__high2float(hv_) + ev1_, 0.f);                                \
  } while (0)
  for (; j + 3 < j1; j += 4) {
    EDGE(j, a0, a1);
    EDGE(j + 1, b0, b1);
    EDGE(j + 2, p0, p1);
    EDGE(j + 3, q0, q1);
  }
  for (; j < j1; ++j) EDGE(j, a0, a1);
#undef EDGE
  a0 += b0 + p0 + q0; a1 += b1 + p1 + q1;
  int di = d * 64 + lane;
  __half2 hd = h2[di];
  reinterpret_cast<__half2*>(hpa16)[di] =
      __floats2half2_rn(__low2float(hd) + a0, __high2float(hd) + a1);
}

// ---------------------------------------------------------------------------
// fp16 MFMA GEMM, K=128 fixed. C[M x ldc] fp32 (or fp16 when OUT_F16).
// A [M][128] f16 row-major; Bt [ldc][128] f16 with Bt[c][k] = W[k][c].
// Block: 64 rows x 128 cols, 4 waves in 2x2, wave tile 32x64.
// A is read DIRECTLY global->VGPR (its layout already matches the fragment);
// only B goes through LDS (35 KB). A reads may run past row M-1 into adjacent
// workspace (valid memory); garbage rows are never stored (row-local MFMA).
// STATS: fused column sum/sumsq -> atomicAdd into stats[0:ldc], stats[ldc:2ldc].
template<bool HAS_BIAS, bool HAS_ROWBIAS, bool OUT_F16, bool STATS>
__global__ __launch_bounds__(256) void k_mgemm(
    const __half* __restrict__ A, const __half* __restrict__ Bt,
    const float* __restrict__ bias, const float* __restrict__ bias2,
    const float* __restrict__ rowbias, const int* __restrict__ batch,
    float* __restrict__ Cf, __half* __restrict__ Ch,
    float* __restrict__ stats, int ldc, int M) {
  __shared__ _Float16 Bsh[128][136];   // +8 pad: row stride 272 B
  int tid = threadIdx.x;
  int m0 = blockIdx.x * 64;
  int c0 = blockIdx.y * 128;
  int wid = tid >> 6, lane = tid & 63;
  int wr = wid >> 1, wc = wid & 1;        // 2x2 wave grid, wave tile 32x64
  int lrow = lane & 15;
  int lk = (lane >> 4) * 8;

  // A fragments: direct global loads (issue before B staging for overlap)
  f16x8 af[4][2];
#pragma unroll
  for (int kk = 0; kk < 4; ++kk)
#pragma unroll
    for (int fm = 0; fm < 2; ++fm)
      af[kk][fm] = *reinterpret_cast<const f16x8*>(
          A + (m0 + wr * 32 + fm * 16 + lrow) * 128 + kk * 32 + lk);

  // stage B: 128 rows x 16 chunks = 2048 chunks
#pragma unroll
  for (int it = 0; it < 8; ++it) {
    int idx = it * 256 + tid;
    int r = idx >> 4, ck = idx & 15;
    f16x8 v = *reinterpret_cast<const f16x8*>(Bt + ((c0 + r) << 7) + ck * 8);
    *reinterpret_cast<f16x8*>(&Bsh[r][ck * 8]) = v;
  }
  __syncthreads();

  f32x4 acc[2][4];
#pragma unroll
  for (int fm = 0; fm < 2; ++fm)
#pragma unroll
    for (int fn = 0; fn < 4; ++fn) acc[fm][fn] = (f32x4){0.f, 0.f, 0.f, 0.f};

#pragma unroll
  for (int kk = 0; kk < 4; ++kk) {
    f16x8 bf[4];
#pragma unroll
    for (int fn = 0; fn < 4; ++fn)
      bf[fn] = *reinterpret_cast<const f16x8*>(&Bsh[wc * 64 + fn * 16 + lrow][kk * 32 + lk]);
#pragma unroll
    for (int fm = 0; fm < 2; ++fm)
#pragma unroll
      for (int fn = 0; fn < 4; ++fn)
        acc[fm][fn] = __builtin_amdgcn_mfma_f32_16x16x32_f16(af[kk][fm], bf[fn], acc[fm][fn], 0, 0, 0);
  }

  // epilogue (+ optional fused column stats)
  float ss[4], ss2[4];
#pragma unroll
  for (int fn = 0; fn < 4; ++fn) { ss[fn] = 0.f; ss2[fn] = 0.f; }
#pragma unroll
  for (int fn = 0; fn < 4; ++fn) {
    int col = c0 + wc * 64 + fn * 16 + lrow;
    float bb = HAS_BIAS ? bias[col] : 0.f;
    if (HAS_BIAS && bias2 != nullptr) bb += bias2[col];
#pragma unroll
    for (int fm = 0; fm < 2; ++fm) {
      int grb = m0 + wr * 32 + fm * 16 + (lane >> 4) * 4;
#pragma unroll
      for (int j = 0; j < 4; ++j) {
        int gr = grb + j;
        if (gr < M) {
          float v = acc[fm][fn][j] + bb;
          if (HAS_ROWBIAS)
            v += rowbias[batch[gr] * ldc + col];
          if (STATS) { ss[fn] += v; ss2[fn] += v * v; }
          if (OUT_F16)
            Ch[(long long)gr * ldc + col] = __float2half(v);
          else
            Cf[(long long)gr * ldc + col] = v;
        }
      }
    }
  }
  if (STATS) {
    __shared__ float sred[2][4][4][16];   // [s|s2][wid][fn][lrow]
#pragma unroll
    for (int fn = 0; fn < 4; ++fn) {
      float s = ss[fn], s2 = ss2[fn];
      s += __shfl_xor(s, 16);  s += __shfl_xor(s, 32);
      s2 += __shfl_xor(s2, 16); s2 += __shfl_xor(s2, 32);
      if (lane < 16) { sred[0][wid][fn][lane] = s; sred[1][wid][fn][lane] = s2; }
    }
    __syncthreads();
    if (wr == 0 && lane < 16) {           // waves 0,1 combine with waves 2,3
#pragma unroll
      for (int fn = 0; fn < 4; ++fn) {
        int col = c0 + wc * 64 + fn * 16 + lane;
        atomicAdd(&stats[col],       sred[0][wid][fn][lane] + sred[0][wid + 2][fn][lane]);
        atomicAdd(&stats[ldc + col], sred[1][wid][fn][lane] + sred[1][wid + 2][fn][lane]);
      }
    }
  }
}

// ---------------------------------------------------------------------------
// Generic fp32 vector GEMM for the small (G-row) matmuls.
// STATS: fused column sum/sumsq into stats[0:128], stats[ldw:ldw+128] via LDS.
template<int K, bool HAS_BIAS, bool HAS_ROWBIAS, bool RELU, bool STATS>
__global__ __launch_bounds__(256) void k_gemm(
    const float* __restrict__ A1,
    const float* __restrict__ W, int ldw,
    const float* __restrict__ bias,
    const float* __restrict__ rowbias, const int* __restrict__ batch,
    float* __restrict__ C, float* __restrict__ stats, int M) {
  __shared__ float As[32 * K];
  constexpr int K4 = K / 4;
  int tid = threadIdx.x;
  int m0 = blockIdx.x * 32;
#pragma unroll
  for (int it = 0; it < K / 32; ++it) {
    int e4 = it * 256 + tid;
    int r = e4 / K4;
    int k4 = e4 % K4;
    int gr = m0 + r;
    float4 v = make_float4(0.f, 0.f, 0.f, 0.f);
    if (gr < M) v = reinterpret_cast<const float4*>(A1)[(long long)gr * K4 + k4];
    reinterpret_cast<float4*>(As)[e4] = v;
  }
  __shared__ float cs[128], cs2[128];
  if (STATS && tid < 128) { cs[tid] = 0.f; cs2[tid] = 0.f; }
  __syncthreads();

  int cg = tid & 31;
  int rg = tid >> 5;
  int col = blockIdx.y * 128 + cg * 4;
  float4 acc[4];
#pragma unroll
  for (int j = 0; j < 4; ++j) acc[j] = make_float4(0.f, 0.f, 0.f, 0.f);
  const float4* W4 = reinterpret_cast<const float4*>(W);
  const float4* As4 = reinterpret_cast<const float4*>(As);
#pragma unroll 8
  for (int k = 0; k < K; k += 4) {
    float4 w0 = W4[((k + 0) * ldw + col) >> 2];
    float4 w1 = W4[((k + 1) * ldw + col) >> 2];
    float4 w2 = W4[((k + 2) * ldw + col) >> 2];
    float4 w3 = W4[((k + 3) * ldw + col) >> 2];
#pragma unroll
    for (int j = 0; j < 4; ++j) {
      float4 a = As4[(rg + j * 8) * K4 + (k >> 2)];
      acc[j].x += a.x * w0.x + a.y * w1.x + a.z * w2.x + a.w * w3.x;
      acc[j].y += a.x * w0.y + a.y * w1.y + a.z * w2.y + a.w * w3.y;
      acc[j].z += a.x * w0.z + a.y * w1.z + a.z * w2.z + a.w * w3.z;
      acc[j].w += a.x * w0.w + a.y * w1.w + a.z * w2.w + a.w * w3.w;
    }
  }
  float4 bb = make_float4(0.f, 0.f, 0.f, 0.f);
  if (HAS_BIAS) bb = reinterpret_cast<const float4*>(bias)[blockIdx.y * 32 + cg];
  float ps[4] = {0.f, 0.f, 0.f, 0.f}, ps2[4] = {0.f, 0.f, 0.f, 0.f};
#pragma unroll
  for (int j = 0; j < 4; ++j) {
    int gr = m0 + rg + j * 8;
    if (gr < M) {
      float4 v = acc[j];
      v.x += bb.x; v.y += bb.y; v.z += bb.z; v.w += bb.w;
      if (HAS_ROWBIAS) {
        int b = batch[gr];
        float4 rb = reinterpret_cast<const float4*>(rowbias)[((long long)b * ldw + col) >> 2];
        v.x += rb.x; v.y += rb.y; v.z += rb.z; v.w += rb.w;
      }
      if (RELU) {
        v.x = fmaxf(v.x, 0.f); v.y = fmaxf(v.y, 0.f);
        v.z = fmaxf(v.z, 0.f); v.w = fmaxf(v.w, 0.f);
      }
      if (STATS) {
        ps[0] += v.x; ps2[0] += v.x * v.x;
        ps[1] += v.y; ps2[1] += v.y * v.y;
        ps[2] += v.z; ps2[2] += v.z * v.z;
        ps[3] += v.w; ps2[3] += v.w * v.w;
      }
      reinterpret_cast<float4*>(C)[((long long)gr * ldw + col) >> 2] = v;
    }
  }
  if (STATS) {
#pragma unroll
    for (int jc = 0; jc < 4; ++jc) {
      atomicAdd(&cs[cg * 4 + jc], ps[jc]);
      atomicAdd(&cs2[cg * 4 + jc], ps2[jc]);
    }
    __syncthreads();
    if (tid < 128) {
      atomicAdd(&stats[blockIdx.y * 128 + tid], cs[tid]);
      atomicAdd(&stats[ldw + blockIdx.y * 128 + tid], cs2[tid]);
    }
  }
}

// ---------------------------------------------------------------------------
// h16 = (half) relu(bn(z16)); half2 lanes, grid = N*64/256 = 12500 exact
__global__ void k_bn16(const __half* __restrict__ X16, const float* __restrict__ stats,
                       const float* __restrict__ gam, const float* __restrict__ beta,
                       __half* __restrict__ out16, float invM) {
  int i2 = blockIdx.x * 256 + threadIdx.x;
  int c = (i2 & 63) * 2;
  __half2 xv = reinterpret_cast<const __half2*>(X16)[i2];
  float m0 = stats[c] * invM;
  float v0 = stats[128 + c] * invM - m0 * m0;
  float m1 = stats[c + 1] * invM;
  float v1 = stats[128 + c + 1] * invM - m1 * m1;
  float r0 = fmaxf((__low2float(xv) - m0) * rsqrtf(v0 + EPS) * gam[c] + beta[c], 0.f);
  float r1 = fmaxf((__high2float(xv) - m1) * rsqrtf(v1 + EPS) * gam[c + 1] + beta[c + 1], 0.f);
  reinterpret_cast<__half2*>(out16)[i2] = __floats2half2_rn(r0, r1);
}

// pooled[g][c] = sum over graph-g rows of relu(bn(z2_16[r][c])).
// Per-graph blocks via gstart (batch sorted): atomic-free, no pre-zero needed.
__global__ void k_pool(const __half* __restrict__ z2_16, const float* __restrict__ stats,
                       const float* __restrict__ gam, const float* __restrict__ beta,
                       const int* __restrict__ gstart, float* __restrict__ pooled) {
  int g = blockIdx.x;
  int c = blockIdx.y * 128 + threadIdx.x;   // grid (G,2) x 128 threads
  const float invM = 1.f / (float)N;
  float mean = stats[c] * invM;
  float var = stats[256 + c] * invM - mean * mean;
  float scale = rsqrtf(var + EPS) * gam[c];
  float shift = beta[c] - mean * scale;
  int r0 = gstart[g], r1 = gstart[g + 1];
  float acc = 0.f;
  for (int r = r0; r < r1; ++r) {
    float v = __half2float(z2_16[(long long)r * 256 + c]);
    acc += fmaxf(v * scale + shift, 0.f);
  }
  pooled[g * 256 + c] = acc;
}

// vn = relu(bn(zvn)); also write into hg concat buffer at layer offset
__global__ void k_vnapply(const float* __restrict__ zvn, const float* __restrict__ stats,
                          const float* __restrict__ gam, const float* __restrict__ beta,
                          float* __restrict__ vn, float* __restrict__ hgbuf, int layer) {
  int idx = blockIdx.x * 256 + threadIdx.x;  // G*H = 65536
  int c = idx & 127;
  int g = idx >> 7;
  const float invM = 1.f / (float)G;
  float mean = stats[c] * invM;
  float var = stats[128 + c] * invM - mean * mean;
  float v = fmaxf((zvn[idx] - mean) * rsqrtf(var + EPS) * gam[c] + beta[c], 0.f);
  vn[idx] = v;
  hgbuf[g * 384 + layer * 128 + c] = v;
}

// out[g] = hg2[g] @ pred_W2 + b2   (one wave per graph)
__global__ void k_pred2(const float* __restrict__ hg2, const float* __restrict__ W2,
                        const float* __restrict__ b2, float* __restrict__ out) {
  int g = blockIdx.x;
  int lane = threadIdx.x;
  float s = 0.f;
  for (int k = lane; k < 384; k += 64) s += hg2[g * 384 + k] * W2[k];
  for (int off = 32; off; off >>= 1) s += __shfl_down(s, off);
  if (lane == 0) out[g] = s + b2[0];
}

// ---------------------------------------------------------------------------
extern "C" void kernel_launch(void* const* d_in, const int* in_sizes, int n_in,
                              void* d_out, int out_size, void* d_ws, size_t ws_size,
                              hipStream_t stream) {
  const float* x         = (const float*)d_in[0];
  const float* edge_attr = (const float*)d_in[1];
  const float* atom_W    = (const float*)d_in[2];
  const float* atom_b    = (const float*)d_in[3];
  const float* vn_emb    = (const float*)d_in[4];
  const float* conv_We   = (const float*)d_in[5];
  const float* conv_be   = (const float*)d_in[6];
  const float* conv_W    = (const float*)d_in[7];
  const float* conv_b    = (const float*)d_in[8];
  const float* conv_g    = (const float*)d_in[9];
  const float* conv_beta = (const float*)d_in[10];
  const float* vn1_W     = (const float*)d_in[11];
  const float* vn1_b     = (const float*)d_in[12];
  const float* vn1_g     = (const float*)d_in[13];
  const float* vn1_beta  = (const float*)d_in[14];
  const float* vn2_W     = (const float*)d_in[15];
  const float* vn2_b     = (const float*)d_in[16];
  const float* vn2_g     = (const float*)d_in[17];
  const float* vn2_beta  = (const float*)d_in[18];
  const float* pred_W1   = (const float*)d_in[19];
  const float* pred_b1   = (const float*)d_in[20];
  const float* pred_W2   = (const float*)d_in[21];
  const float* pred_b2   = (const float*)d_in[22];
  const int*   eidx      = (const int*)d_in[23];
  const int*   batch     = (const int*)d_in[24];
  const int* src = eidx;
  const int* dst = eidx + E;

  // Workspace layout (units: 4-byte slots). Total ~24.1M slots = ~96.5 MB.
  float* ws    = (float*)d_ws;
  __half* h16  = (__half*)ws;                  // N*128 halves
  float* bufB  = ws + NH / 2;                  // 2*NH slots
  __half* hpa16= (__half*)bufB;                // N*128 halves  [B 0 .. NH/2)
  __half* z16  = (__half*)(bufB + NH / 2);     // N*128 halves  [B NH/2 .. NH)
  __half* x16  = z16;                          // alias (dead before conv gemm)
  __half* z2_16= (__half*)(bufB + NH);         // N*256 halves  [B NH .. 2NH)
  float* smallz= bufB + 2 * NH;
  float* U     = smallz;                       // G*256
  float* pooled= U + G * 256;                  // G*256
  float* zvn   = pooled + G * 256;             // G*128
  float* vn    = zvn + G * 128;                // G*128
  float* hgbuf = vn + G * 128;                 // G*384
  float* hg2   = hgbuf + G * 384;              // G*384
  float* statsz= hg2 + G * 384;                // 3*1024 (per-layer slices)
  int*   gstart= (int*)(statsz + 3 * 1024);    // G+1 (pad 516)
  __half* atomWt = (__half*)(gstart + 516);    // 128*128 halves
  __half* convWt = atomWt + 16384;             // 3 * 128*128
  __half* z2Wt   = convWt + 3 * 16384;         // 3 * 256*128
  int*  off    = (int*)(z2Wt + 3 * 32768);     // N+1 (padded 50002)
  int*  srcp   = off + 50002;                  // E ints (dst-sorted src*64)
  __half* eap  = (__half*)(srcp + E);          // E*16 halves (dst-sorted fp16 ea)
  // CSR build temporaries (dead before first k_agg) alias bufB:
  int* cnt  = (int*)bufB;                      // N
  int* cur  = cnt + N;                         // N
  int* bsum = cur + N;                         // NB_SCAN

  dim3 b256(256);

  // ---- CSR build (once; edge_index identical across layers) ----
  hipMemsetAsync(cnt, 0, (size_t)(2 * N + NB_SCAN) * 4, stream);  // cnt+cur+bsum
  hipMemsetAsync(statsz, 0, 3 * 1024 * 4, stream);
  k_hist<<<E / 256, b256, 0, stream>>>(dst, cnt);
  k_scan_block<<<NB_SCAN, b256, 0, stream>>>(cnt, off, bsum);
  k_scan_bsum<<<1, b256, 0, stream>>>(bsum);
  k_scan_add<<<NB_SCAN, b256, 0, stream>>>(off, bsum);
  k_scatter<<<E / 256, b256, 0, stream>>>(src, dst, off, cur, srcp, eap, edge_attr);
  k_gstart<<<1, G, 0, stream>>>(batch, gstart);

  k_init_vn<<<G * 128 / 256, b256, 0, stream>>>(vn_emb, vn);

  // ---- weight/input fp16 prep ----
  k_tof16<<<(N * 128 / 4 + 255) / 256, b256, 0, stream>>>(x, x16, N * 128 / 4);
  k_wt<<<dim3(64, 1), b256, 0, stream>>>(atom_W, atomWt, 128, 0, 128, 0, 0);
  k_wt<<<dim3(64, 3), b256, 0, stream>>>(conv_W, convWt, 128, 0, 128, 16384, 16384);
  k_wt<<<dim3(128, 3), b256, 0, stream>>>(vn1_W, z2Wt, 256, 128, 256, 65536, 32768);

  // h16 = x16 @ atom_W + (atom_b + vn_emb)   (layer-0 addvn folded)
  k_mgemm<true, false, true, false><<<dim3(782, 1), b256, 0, stream>>>(
      x16, atomWt, atom_b, vn_emb, nullptr, nullptr, nullptr, h16, nullptr, 128, N);

  for (int i = 0; i < 3; ++i) {
    float* SZ = statsz + i * 1024;   // conv: +0 (256), z2: +256 (512), zvn: +768 (256)
    if (i > 0) k_addvn16<<<12500, b256, 0, stream>>>(h16, vn, batch);
    // hpa16 = h16 + sum_in relu(h16[src] + ea@We + be)  (2 half-grid dispatches)
    k_agg<<<6250, b256, 0, stream>>>(eap, conv_We + i * 2048, conv_be + i * 128,
                                     off, srcp, h16, hpa16, 0);
    k_agg<<<6250, b256, 0, stream>>>(eap, conv_We + i * 2048, conv_be + i * 128,
                                     off, srcp, h16, hpa16, 25000);
    // z16 = hpa16 @ conv_W[i] + conv_b[i]   (MFMA, fp16 out, fused stats)
    k_mgemm<true, false, true, true><<<dim3(782, 1), b256, 0, stream>>>(
        hpa16, convWt + i * 16384, conv_b + i * 128, nullptr, nullptr, nullptr,
        nullptr, z16, SZ, 128, N);
    // h16 = relu(bn(z16))
    k_bn16<<<12500, b256, 0, stream>>>(z16, SZ, conv_g + i * 128, conv_beta + i * 128,
                                       h16, 1.f / (float)N);
    // U = vn @ vn1_W[i][:128,:] + vn1_b[i]   (512 distinct rows of vn[batch])
    k_gemm<128, true, false, false, false><<<dim3(16, 2), b256, 0, stream>>>(
        vn, vn1_W + i * 256 * 256, 256, vn1_b + i * 256, nullptr, nullptr, U, nullptr, G);
    // z2_16 = h16 @ vn1_W[i][128:,:] + U[batch]   (MFMA, fp16 out, fused stats)
    k_mgemm<false, true, true, true><<<dim3(782, 2), b256, 0, stream>>>(
        h16, z2Wt + i * 32768, nullptr, nullptr, U, batch, nullptr, z2_16,
        SZ + 256, 256, N);
    // pooled[g] = sum relu(bn(z2_16))   (per-graph, atomic-free)
    k_pool<<<dim3(G, 2), dim3(128), 0, stream>>>(
        z2_16, SZ + 256, vn1_g + i * 256, vn1_beta + i * 256, gstart, pooled);
    // zvn = pooled @ vn2_W[i] + vn2_b[i]  (fused stats)
    k_gemm<256, true, false, false, true><<<dim3(16, 1), b256, 0, stream>>>(
        pooled, vn2_W + i * 256 * 128, 128, vn2_b + i * 128, nullptr, nullptr,
        zvn, SZ + 768, G);
    k_vnapply<<<G * 128 / 256, b256, 0, stream>>>(
        zvn, SZ + 768, vn2_g + i * 128, vn2_beta + i * 128, vn, hgbuf, i);
  }
  // hg2 = relu(hgbuf @ pred_W1 + pred_b1)
  k_gemm<384, true, false, true, false><<<dim3(16, 3), b256, 0, stream>>>(
      hgbuf, pred_W1, 384, pred_b1, nullptr, nullptr, hg2, nullptr, G);
  k_pred2<<<G, 64, 0, stream>>>(hg2, pred_W2, pred_b2, (float*)d_out);
}